// Round 1
// 552.132 us; speedup vs baseline: 1.0460x; 1.0460x over previous
//
#include <hip/hip_runtime.h>

typedef short bf16x8 __attribute__((ext_vector_type(8)));
typedef short bf16x4 __attribute__((ext_vector_type(4)));
typedef float f32x4 __attribute__((ext_vector_type(4)));

#define DEVI __device__ __forceinline__

constexpr int N   = 32768;
constexpr int C   = 128;
constexpr int E   = 524288;
constexpr float EPSV = 1e-5f;
constexpr int UT_BLOCKS = 256;
constexpr int HB  = 64;          // histogram blocks per edge-array (src / dst)
constexpr int EPB = E / HB;      // 8192 edges per histogram block

DEVI float bf2f(ushort u){ return __uint_as_float(((uint)u) << 16); }
DEVI ushort f2bf(float f){
  uint u = __float_as_uint(f);
  return (ushort)((u + 0x7fffu + ((u >> 16) & 1u)) >> 16);
}
DEVI float sane(float v){ if (!(v == v)) return 0.f; return fminf(fmaxf(v, -1e30f), 1e30f); }
DEVI bool mode_fp32(const uint* lmraw){ return (lmraw[0] & 0xffffu) == 0u; }

// ---------------- canonical small-input table ----------------
constexpr int CSZ[28] = {128,1,16384,128,16384,128,16384,128,16384,128,81920,128,
                         1,16384,49152,384,16384,128,32768,256,32768,128,
                         128,128,128,128,128,128};
constexpr int COF[28] = {0,128,192,16576,16704,33088,33216,49600,49728,66112,
                         66240,148160,148288,148352,164736,213888,214272,230656,
                         230784,263552,263808,296576,296704,296832,296960,297088,
                         297216,297344};
constexpr int CAN_SMALL_TOTAL = 297472;

struct CvtArgs { const void* src[28]; };

__global__ __launch_bounds__(256) void convert_small(CvtArgs a, ushort* __restrict__ can,
                                                     const uint* __restrict__ lmraw)
{
  bool f32 = mode_fp32(lmraw);
  int idx = blockIdx.x * 256 + threadIdx.x;
  #pragma unroll 1
  for (int s = 0; s < 28; s++) {
    if (idx < CSZ[s]) {
      ushort v = f32 ? f2bf(((const float*)a.src[s])[idx])
                     : ((const ushort*)a.src[s])[idx];
      can[COF[s] + idx] = v;
      return;
    }
    idx -= CSZ[s];
  }
}

__global__ __launch_bounds__(256) void convert_big(const void* __restrict__ xs,
    const void* __restrict__ Us, ushort* __restrict__ canx, ushort* __restrict__ canu,
    const uint* __restrict__ lmraw)
{
  bool f32 = mode_fp32(lmraw);
  size_t e = ((size_t)blockIdx.x * 256 + threadIdx.x) * 4;
  bool isU = e >= (size_t)N * C;
  size_t off = isU ? e - (size_t)N * C : e;
  const void* src = isU ? Us : xs;
  ushort* dst = isU ? canu : canx;
  ushort4 o;
  if (f32) {
    float4 v = *(const float4*)((const float*)src + off);
    o.x = f2bf(v.x); o.y = f2bf(v.y); o.z = f2bf(v.z); o.w = f2bf(v.w);
  } else {
    o = *(const ushort4*)((const ushort*)src + off);
  }
  *(ushort4*)(dst + off) = o;
}

// ---------------- edge prep: LDS-private histograms (no device atomics) ----
// Block b (of 2*HB) owns edge indices [b*EPB, (b+1)*EPB) of the flattened
// [src | dst] index stream. 16-bit packed LDS bins: per-block bin count is
// bounded by EPB=8192 < 65536, so packing is unconditionally overflow-safe.
__global__ __launch_bounds__(1024) void hist_lds(const int* __restrict__ ei,
    int* __restrict__ cei, ushort* __restrict__ part)
{
  __shared__ uint hist[N / 2];          // 64 KB, two bins per word
  int t = threadIdx.x;
  int b = blockIdx.x;
  bool i64 = ((ei[1] | ei[3] | ei[5] | ei[7]) == 0);
  size_t j0 = (size_t)b * EPB;
  #pragma unroll
  for (int i = t; i < N / 2; i += 1024) hist[i] = 0u;
  __syncthreads();
  for (int k = t; k < EPB; k += 1024) {
    size_t j = j0 + k;
    int v = (i64 ? ei[2 * j] : ei[j]) & (N - 1);
    cei[j] = v;
    atomicAdd(&hist[v >> 1], 1u << ((v & 1) * 16));
  }
  __syncthreads();
  uint* po = (uint*)(part + (size_t)b * N);
  for (int i = t; i < N / 2; i += 1024) po[i] = hist[i];
}

// fold partials: src totals -> dis, dst totals -> cdt
__global__ __launch_bounds__(256) void reduce_cnt(const ushort* __restrict__ part,
    int* __restrict__ cdt, float* __restrict__ dis)
{
  int d = blockIdx.x * 256 + threadIdx.x;
  int s = 0, tt = 0;
  #pragma unroll 8
  for (int b = 0; b < HB; b++) s  += part[(size_t)b * N + d];
  #pragma unroll 8
  for (int b = 0; b < HB; b++) tt += part[(size_t)(HB + b) * N + d];
  cdt[d] = tt;
  dis[d] = s > 0 ? rsqrtf((float)s) : 0.f;
}

__global__ __launch_bounds__(1024) void scan_kernel(const int* __restrict__ cnt,
                                                    int* __restrict__ row_ptr)
{
  __shared__ int sums[1024];
  int t = threadIdx.x;
  int loc[32]; int s = 0;
  int base = t * 32;
  #pragma unroll
  for (int i = 0; i < 32; i++) { loc[i] = s; s += cnt[base + i]; }
  sums[t] = s;
  __syncthreads();
  for (int off = 1; off < 1024; off <<= 1) {
    int v = (t >= off) ? sums[t - off] : 0;
    __syncthreads();
    sums[t] += v;
    __syncthreads();
  }
  int pre = (t == 0) ? 0 : sums[t - 1];
  #pragma unroll
  for (int i = 0; i < 32; i++) row_ptr[base + i] = pre + loc[i];
}

// per-hist-block slot bases: off2[b][d] = rp[d] + sum_{b'<b} partD[b'][d]
__global__ __launch_bounds__(256) void off_kernel(const int* __restrict__ rp,
    const ushort* __restrict__ part, int* __restrict__ off2)
{
  int d = blockIdx.x * 256 + threadIdx.x;
  int run = rp[d];
  #pragma unroll 8
  for (int b = 0; b < HB; b++) {
    off2[(size_t)b * N + d] = run;
    run += part[(size_t)(HB + b) * N + d];
  }
}

// deterministic scatter: block b replays its edge slice, ranks via LDS atomics
__global__ __launch_bounds__(1024) void edge_scatter(const int* __restrict__ cei,
    const int* __restrict__ off2, const float* __restrict__ dis,
    int2* __restrict__ ep)
{
  __shared__ int base[N];               // 128 KB slot cursors
  int t = threadIdx.x;
  int b = blockIdx.x;                   // 0..HB-1
  for (int i = t; i < N; i += 1024) base[i] = off2[(size_t)b * N + i];
  __syncthreads();
  size_t e0 = (size_t)b * EPB;
  for (int k = t; k < EPB; k += 1024) {
    size_t e = e0 + k;
    int s = cei[e], d = cei[e + E];
    int slot = atomicAdd(&base[d], 1);
    int2 v; v.x = s; v.y = __float_as_int(dis[s] * dis[d]);
    ep[slot] = v;
  }
}

// ---------------- weight pre-transpose ----------------
constexpr int WT_SPA1 = 0;
constexpr int WT_SPA2 = 16384;
constexpr int WT_SPE1 = 32768;
constexpr int WT_SPE2 = 49152;
constexpr int WT_PROJ = 65536;
constexpr int WT_CHEB = 81920;    // 128 x 640 (concat layout)
constexpr int WT_QKV  = 163840;   // 384 x 128
constexpr int WT_WOUT = 212992;
constexpr int WT_MLP1 = 229376;   // 256 x 128
constexpr int WT_MLP2 = 262144;   // 128 x 256
constexpr int WT_TOTAL = 294912;

__global__ __launch_bounds__(256) void zero_kernel(int* __restrict__ p, int n)
{
  int i = blockIdx.x * 256 + threadIdx.x;
  if (i < n) p[i] = 0;
}

__global__ __launch_bounds__(256) void transpose_weights(
    const ushort* __restrict__ spa1, const ushort* __restrict__ spa2,
    const ushort* __restrict__ spe1, const ushort* __restrict__ spe2,
    const ushort* __restrict__ proj, const ushort* __restrict__ cheb,
    const ushort* __restrict__ qkv,  const ushort* __restrict__ wout,
    const ushort* __restrict__ mlp1, const ushort* __restrict__ mlp2,
    ushort* __restrict__ wt)
{
  int i = blockIdx.x * 256 + threadIdx.x;
  if (i < 81920) {
    int m = i >> 14, r = i & 16383; int k = r >> 7, n = r & 127;
    const ushort* src = m==0?spa1 : m==1?spa2 : m==2?spe1 : m==3?spe2 : proj;
    wt[m*16384 + n*128 + k] = src[r];
  } else if (i < 163840) {
    int j = i - 81920; int m = j >> 14, r = j & 16383; int k = r >> 7, n = r & 127;
    wt[WT_CHEB + n*640 + m*128 + k] = cheb[j];
  } else if (i < 212992) {
    int j = i - 163840; int k = j / 384, n = j % 384;
    wt[WT_QKV + n*128 + k] = qkv[j];
  } else if (i < 229376) {
    int j = i - 212992; int k = j >> 7, n = j & 127;
    wt[WT_WOUT + n*128 + k] = wout[j];
  } else if (i < 262144) {
    int j = i - 229376; int k = j >> 8, n = j & 255;
    wt[WT_MLP1 + n*128 + k] = mlp1[j];
  } else if (i < WT_TOTAL) {
    int j = i - 262144; int k = j >> 7, n = j & 127;
    wt[WT_MLP2 + n*256 + k] = mlp2[j];
  }
}

// ---------------- LDS-staged MFMA GEMM ----------------
template<int K, int COLS, bool RELU, int OMODE, bool BIAS, bool RES, int ASTR, int OSTR>
__global__ __launch_bounds__(256) void gemm_lds(
    const ushort* __restrict__ A, const ushort* __restrict__ WT,
    const ushort* __restrict__ bias, const ushort* __restrict__ res,
    void* __restrict__ outp)
{
  constexpr int NSEG = COLS / 128;
  constexpr int NKC = K / 128;
  constexpr int BP = 136;
  __shared__ ushort Bs[128 * BP];
  int tid = threadIdx.x;
  int lane = tid & 63, wave = tid >> 6;
  int quad = lane >> 4, l16 = lane & 15;
  int seg = (NSEG > 1) ? (blockIdx.x % NSEG) : 0;
  int rb  = (NSEG > 1) ? (blockIdx.x / NSEG) : blockIdx.x;
  int row0 = rb * 64 + wave * 16;
  const ushort* wseg = WT + (size_t)(seg * 128) * K;

  f32x4 acc[8];
  #pragma unroll
  for (int nt = 0; nt < 8; nt++) acc[nt] = (f32x4){0.f, 0.f, 0.f, 0.f};

  for (int kc = 0; kc < NKC; kc++) {
    if (kc) __syncthreads();
    #pragma unroll
    for (int i = tid; i < 2048; i += 256) {
      int col = i >> 4, ko = (i & 15) * 8;
      *(bf16x8*)&Bs[col * BP + ko] =
          *(const bf16x8*)(wseg + (size_t)col * K + kc * 128 + ko);
    }
    __syncthreads();
    bf16x8 a[4];
    const ushort* ap = A + (size_t)(row0 + l16) * ASTR + kc * 128 + quad * 8;
    #pragma unroll
    for (int kk = 0; kk < 4; kk++) a[kk] = *(const bf16x8*)(ap + kk * 32);
    #pragma unroll
    for (int kk = 0; kk < 4; kk++) {
      #pragma unroll
      for (int nt = 0; nt < 8; nt++) {
        bf16x8 b = *(const bf16x8*)(&Bs[(nt * 16 + l16) * BP + kk * 32 + quad * 8]);
        acc[nt] = __builtin_amdgcn_mfma_f32_16x16x32_bf16(a[kk], b, acc[nt], 0, 0, 0);
      }
    }
  }

  #pragma unroll
  for (int nt = 0; nt < 8; nt++) {
    int col = seg * 128 + nt * 16 + l16;
    float bv = 0.f;
    if (BIAS) bv = bf2f(bias[col]);
    #pragma unroll
    for (int r = 0; r < 4; r++) {
      int row = row0 + quad * 4 + r;
      size_t oi = (size_t)row * OSTR + col;
      float v = acc[nt][r] + bv;
      if (RES) v += bf2f(res[(size_t)row * COLS + col]);
      if (RELU) v = fmaxf(v, 0.f);
      if (OMODE == 0)      ((ushort*)outp)[oi] = f2bf(v);
      else if (OMODE == 1) ((float*)outp)[oi] = v;
      else                 ((float*)outp)[oi] += v;
    }
  }
}

// ---------------- fused lhat / Chebyshev recurrence ----------------
__global__ __launch_bounds__(256) void spmm_cheb(
    const int* __restrict__ row_ptr, const int2* __restrict__ ep,
    const ushort* __restrict__ v,
    const ushort* __restrict__ txprev, ushort* __restrict__ txout,
    const ushort* __restrict__ lambda_max, int first, int str)
{
  int wave = threadIdx.x >> 6, lane = threadIdx.x & 63;
  int sub = lane >> 4, l16 = lane & 15;
  int d = blockIdx.x * 4 + wave;
  float lm = bf2f(lambda_max[0]);
  float scale = 2.f / lm;
  if (!(scale == scale) || fabsf(scale) > 1e6f) scale = 1.f;
  int beg = row_ptr[d];
  int end = (d == N - 1) ? E : row_ptr[d + 1];
  float acc[8] = {0.f,0.f,0.f,0.f,0.f,0.f,0.f,0.f};
  for (int jb = beg; jb < end; jb += 4) {
    int j = jb + sub;
    bool ok = j < end;
    int2 e2 = ep[ok ? j : beg];
    int s = e2.x & (N - 1);
    float w = ok ? __int_as_float(e2.y) : 0.f;
    bf16x8 vv = *(const bf16x8*)(v + (size_t)s * str + l16 * 8);
    #pragma unroll
    for (int i = 0; i < 8; i++) acc[i] += w * bf2f((ushort)vv[i]);
  }
  #pragma unroll
  for (int i = 0; i < 8; i++) {
    acc[i] += __shfl_xor(acc[i], 16);
    acc[i] += __shfl_xor(acc[i], 32);
  }
  if (sub == 0) {
    bf16x8 vd = *(const bf16x8*)(v + (size_t)d * str + l16 * 8);
    bf16x8 tp;
    if (!first) tp = *(const bf16x8*)(txprev + (size_t)d * str + l16 * 8);
    bf16x8 ov;
    #pragma unroll
    for (int i = 0; i < 8; i++) {
      float r = (scale - 1.f) * bf2f((ushort)vd[i]) - scale * acc[i];
      if (!first) r = 2.f * r - bf2f((ushort)tp[i]);
      ov[i] = (short)f2bf(r);
    }
    *(bf16x8*)(txout + (size_t)d * str + l16 * 8) = ov;
  }
}

// ---------------- U^T @ h_proj partials via MFMA ----------------
__global__ __launch_bounds__(256) void ut_mfma(const ushort* __restrict__ U,
    const ushort* __restrict__ hp, float* __restrict__ parts)
{
  constexpr int RP = 40;
  __shared__ ushort Ut[128 * RP];
  __shared__ ushort Ht[128 * RP];
  int t = threadIdx.x;
  int lane = t & 63, wave = t >> 6;
  int quad = lane >> 4, l16 = lane & 15;

  f32x4 acc[2][8];
  #pragma unroll
  for (int a = 0; a < 2; a++)
    #pragma unroll
    for (int ct = 0; ct < 8; ct++) acc[a][ct] = (f32x4){0.f, 0.f, 0.f, 0.f};

  for (int ch = 0; ch < 4; ch++) {
    int n0 = blockIdx.x * 128 + ch * 32;
    __syncthreads();
    for (int i = t; i < 2048; i += 256) {
      int r2 = i >> 7, c = i & 127;
      uint u0 = U [(size_t)(n0 + r2 * 2) * 128 + c];
      uint u1 = U [(size_t)(n0 + r2 * 2 + 1) * 128 + c];
      *(uint*)&Ut[c * RP + r2 * 2] = (u0 & 0xffffu) | (u1 << 16);
      uint h0 = hp[(size_t)(n0 + r2 * 2) * 128 + c];
      uint h1 = hp[(size_t)(n0 + r2 * 2 + 1) * 128 + c];
      *(uint*)&Ht[c * RP + r2 * 2] = (h0 & 0xffffu) | (h1 << 16);
    }
    __syncthreads();
    bf16x8 bfr[8];
    #pragma unroll
    for (int ct = 0; ct < 8; ct++)
      bfr[ct] = *(const bf16x8*)(&Ht[(ct * 16 + l16) * RP + quad * 8]);
    #pragma unroll
    for (int a = 0; a < 2; a++) {
      int kt = wave * 2 + a;
      bf16x8 af = *(const bf16x8*)(&Ut[(kt * 16 + l16) * RP + quad * 8]);
      #pragma unroll
      for (int ct = 0; ct < 8; ct++)
        acc[a][ct] = __builtin_amdgcn_mfma_f32_16x16x32_bf16(af, bfr[ct], acc[a][ct], 0, 0, 0);
    }
  }

  float* po = parts + (size_t)blockIdx.x * 16384;
  #pragma unroll
  for (int a = 0; a < 2; a++) {
    int kt = wave * 2 + a;
    #pragma unroll
    for (int ct = 0; ct < 8; ct++)
      #pragma unroll
      for (int r = 0; r < 4; r++)
        po[(kt * 16 + quad * 4 + r) * 128 + ct * 16 + l16] = acc[a][ct][r];
  }
}

__global__ __launch_bounds__(256) void reduce_mt(const float* __restrict__ parts,
    const ushort* __restrict__ Lambda, const ushort* __restrict__ gamma,
    ushort* __restrict__ MT)
{
  int e = blockIdx.x * 256 + threadIdx.x;
  int keig = e >> 7, c = e & 127;
  float s = 0.f;
  for (int p = 0; p < UT_BLOCKS; p++) s += parts[(size_t)p * 16384 + e];
  float g = bf2f(gamma[0]);
  float lam = bf2f(Lambda[keig]);
  float sl = __expf(-g * lam * lam);
  MT[c * 128 + keig] = f2bf(sl * s);
}

// ---------------- BatchNorm ----------------
__global__ __launch_bounds__(256) void bn_stats(const float* __restrict__ h,
                                                float* __restrict__ stats)
{
  int c = threadIdx.x & 127, half = threadIdx.x >> 7;
  int r0 = blockIdx.x * 128 + half;
  float s = 0.f, s2 = 0.f;
  for (int i = 0; i < 64; i++) {
    float v = sane(h[(size_t)(r0 + i * 2) * 128 + c]);
    s += v; s2 += v * v;
  }
  atomicAdd(&stats[c], s);
  atomicAdd(&stats[128 + c], s2);
}

__global__ __launch_bounds__(256) void bn_apply(const float* __restrict__ h,
    const float* __restrict__ st, const ushort* __restrict__ gw,
    const ushort* __restrict__ gb, const ushort* __restrict__ add,
    void* __restrict__ out, const uint* __restrict__ lmraw, int final_out)
{
  size_t e = ((size_t)blockIdx.x * 256 + threadIdx.x) * 4;
  int c0 = (int)(e & 127);
  float4 hv = *(const float4*)(h + e);
  float xv[4] = {sane(hv.x), sane(hv.y), sane(hv.z), sane(hv.w)};
  float addv[4] = {0.f, 0.f, 0.f, 0.f};
  if (add) {
    ushort4 av = *(const ushort4*)(add + e);
    addv[0] = bf2f(av.x); addv[1] = bf2f(av.y);
    addv[2] = bf2f(av.z); addv[3] = bf2f(av.w);
  }
  float r[4];
  #pragma unroll
  for (int j = 0; j < 4; j++) {
    int c = c0 + j;
    float mu = st[c] * (1.f / 32768.f);
    float var = fmaxf(st[128 + c] * (1.f / 32768.f) - mu * mu, 0.f);
    r[j] = (xv[j] - mu) * rsqrtf(var + EPSV) * bf2f(gw[c]) + bf2f(gb[c]) + addv[j];
  }
  if (final_out && mode_fp32(lmraw)) {
    float4 o4; o4.x = r[0]; o4.y = r[1]; o4.z = r[2]; o4.w = r[3];
    *(float4*)((float*)out + e) = o4;
  } else {
    ushort4 o;
    o.x = f2bf(r[0]); o.y = f2bf(r[1]); o.z = f2bf(r[2]); o.w = f2bf(r[3]);
    *(ushort4*)((ushort*)out + e) = o;
  }
}

// ---------------- MFMA flash attention ----------------
__global__ __launch_bounds__(256) void attn_mfma(const ushort* __restrict__ qkv,
                                                 ushort* __restrict__ attn)
{
  constexpr int VP = 520;
  __shared__ ushort Vt[32 * VP];
  int b = blockIdx.x;
  int g = b >> 3, hh = (b >> 1) & 3, half = b & 1;
  int lane = threadIdx.x & 63, wave = threadIdx.x >> 6;
  int quad = lane >> 4, l16 = lane & 15;
  const ushort* base = qkv + (size_t)g * 512 * 384;

  for (int i = threadIdx.x; i < 512 * 8; i += 256) {
    int key = i >> 3, d4 = (i & 7) * 4;
    ushort4 v4 = *(const ushort4*)(base + key * 384 + 256 + hh * 32 + d4);
    Vt[(d4 + 0) * VP + key] = v4.x;
    Vt[(d4 + 1) * VP + key] = v4.y;
    Vt[(d4 + 2) * VP + key] = v4.z;
    Vt[(d4 + 3) * VP + key] = v4.w;
  }
  __syncthreads();

  int q0 = half * 256 + wave * 64;
  bf16x8 qf[4];
  #pragma unroll
  for (int i = 0; i < 4; i++)
    qf[i] = *(const bf16x8*)(base + (size_t)(q0 + i * 16 + l16) * 384 + hh * 32 + quad * 8);

  f32x4 O[2][4];
  #pragma unroll
  for (int dt = 0; dt < 2; dt++)
    #pragma unroll
    for (int i = 0; i < 4; i++) O[dt][i] = (f32x4){0.f, 0.f, 0.f, 0.f};
  float lsum[4] = {0.f, 0.f, 0.f, 0.f};
  const float SC = 0.17677669529663687f;

  for (int kt = 0; kt < 32; kt++) {
    bf16x8 kf = *(const bf16x8*)(base + (size_t)(kt * 16 + l16) * 384 + 128 + hh * 32 + quad * 8);
    bf16x8 pf[4];
    #pragma unroll
    for (int i = 0; i < 4; i++) {
      f32x4 s = __builtin_amdgcn_mfma_f32_16x16x32_bf16(kf, qf[i], (f32x4){0.f,0.f,0.f,0.f}, 0, 0, 0);
      float p0 = __expf(fminf(s[0] * SC, 60.f));
      float p1 = __expf(fminf(s[1] * SC, 60.f));
      float p2 = __expf(fminf(s[2] * SC, 60.f));
      float p3 = __expf(fminf(s[3] * SC, 60.f));
      lsum[i] += p0 + p1 + p2 + p3;
      pf[i] = (bf16x8){(short)f2bf(p0), (short)f2bf(p1), (short)f2bf(p2), (short)f2bf(p3), 0, 0, 0, 0};
    }
    #pragma unroll
    for (int dt = 0; dt < 2; dt++) {
      bf16x4 v4 = *(const bf16x4*)(&Vt[(dt * 16 + l16) * VP + kt * 16 + quad * 4]);
      bf16x8 vf = (bf16x8){v4[0], v4[1], v4[2], v4[3], 0, 0, 0, 0};
      #pragma unroll
      for (int i = 0; i < 4; i++)
        O[dt][i] = __builtin_amdgcn_mfma_f32_16x16x32_bf16(vf, pf[i], O[dt][i], 0, 0, 0);
    }
  }

  #pragma unroll
  for (int i = 0; i < 4; i++) {
    float l = lsum[i];
    l += __shfl_xor(l, 16);
    l += __shfl_xor(l, 32);
    lsum[i] = 1.f / l;
  }

  #pragma unroll
  for (int i = 0; i < 4; i++) {
    size_t node = (size_t)g * 512 + q0 + i * 16 + l16;
    #pragma unroll
    for (int dt = 0; dt < 2; dt++) {
      ushort4 o;
      o.x = f2bf(O[dt][i][0] * lsum[i]);
      o.y = f2bf(O[dt][i][1] * lsum[i]);
      o.z = f2bf(O[dt][i][2] * lsum[i]);
      o.w = f2bf(O[dt][i][3] * lsum[i]);
      *(ushort4*)(attn + node * 128 + hh * 32 + dt * 16 + quad * 4) = o;
    }
  }
}

// ---------------- workspace layout (bytes), total 103 MB ----------------
constexpr size_t KB = 1024;
constexpr size_t MB = 1048576;
constexpr size_t OFF_WT    = 0;                 // 576 KB
constexpr size_t OFF_CDT   = 576 * KB;          // 128 KB (cnt_dst totals)
constexpr size_t OFF_RP    = 704 * KB;          // 128 KB
constexpr size_t OFF_DIS   = 832 * KB;          // 128 KB
constexpr size_t OFF_MT    = 960 * KB;          // 32 KB
constexpr size_t OFF_STATS = 1024 * KB;         // 3 KB  [zeroed]
constexpr size_t OFF_CEI   = 6  * MB;           // 4 MB
constexpr size_t OFF_EP    = 10 * MB;           // 4 MB (packed int2 per slot)
constexpr size_t OFF_CANX  = 14 * MB;           // 8 MB; later comb
constexpr size_t OFF_CANU  = 22 * MB;           // 8 MB; later h1
constexpr size_t OFF_CANS  = 30 * MB;           // ~0.6 MB
constexpr size_t OFF_F1    = 31 * MB;           // fp32 16 MB (spec shares, dead before F1)
constexpr size_t OFF_SPEC  = 31 * MB;           // 8 MB
constexpr size_t OFF_HPROJ = 39 * MB;           // 8 MB (tmpA shares; dead before F1 write)
constexpr size_t OFF_TBIG  = 47 * MB;           // 40 MB; later qkv/mlph
constexpr size_t OFF_PARTH = OFF_TBIG;          // 8 MB hist partials (dead before Tbig)
constexpr size_t OFF_OFF2  = OFF_TBIG + 8 * MB; // 8 MB per-block slot bases
constexpr size_t OFF_PARTS = 87 * MB;           // 16 MB; attnb shares; end 103 MB

extern "C" void kernel_launch(void* const* d_in, const int* in_sizes, int n_in,
                              void* d_out, int out_size, void* d_ws, size_t ws_size,
                              hipStream_t stream) {
  (void)in_sizes; (void)n_in; (void)out_size; (void)ws_size;
  const uint* lmraw = (const uint*)d_in[3];
  const int*  ei    = (const int*)d_in[30];

  char* W = (char*)d_ws;
  ushort* wt    = (ushort*)(W + OFF_WT);
  int*    cdt   = (int*)(W + OFF_CDT);
  int*    rp    = (int*)(W + OFF_RP);
  float*  dis   = (float*)(W + OFF_DIS);
  ushort* MT    = (ushort*)(W + OFF_MT);
  float*  stats = (float*)(W + OFF_STATS);
  int*    cei   = (int*)(W + OFF_CEI);
  int2*   ep    = (int2*)(W + OFF_EP);
  ushort* part  = (ushort*)(W + OFF_PARTH);
  int*    off2  = (int*)(W + OFF_OFF2);
  ushort* canx  = (ushort*)(W + OFF_CANX);
  ushort* canu  = (ushort*)(W + OFF_CANU);
  ushort* cs    = (ushort*)(W + OFF_CANS);
  float*  F1    = (float*)(W + OFF_F1);
  ushort* spec  = (ushort*)(W + OFF_SPEC);
  ushort* tmpA  = (ushort*)(W + OFF_HPROJ);
  ushort* hproj = (ushort*)(W + OFF_HPROJ);
  ushort* Tbig  = (ushort*)(W + OFF_TBIG);
  ushort* qkvb  = (ushort*)(W + OFF_TBIG);
  ushort* mlph  = (ushort*)(W + OFF_TBIG);
  float*  parts = (float*)(W + OFF_PARTS);
  ushort* attnb = (ushort*)(W + OFF_PARTS);
  ushort* h1    = (ushort*)(W + OFF_CANU);
  ushort* comb  = (ushort*)(W + OFF_CANX);

  const ushort* cLambda = cs + COF[0];
  const ushort* cLmx    = cs + COF[1];
  const ushort* cSpa1   = cs + COF[2];
  const ushort* cBspa1  = cs + COF[3];
  const ushort* cSpa2   = cs + COF[4];
  const ushort* cBspa2  = cs + COF[5];
  const ushort* cSpe1   = cs + COF[6];
  const ushort* cBspe1  = cs + COF[7];
  const ushort* cSpe2   = cs + COF[8];
  const ushort* cBspe2  = cs + COF[9];
  const ushort* cCheb   = cs + COF[10];
  const ushort* cChebB  = cs + COF[11];
  const ushort* cGam    = cs + COF[12];
  const ushort* cProj   = cs + COF[13];
  const ushort* cQkv    = cs + COF[14];
  const ushort* cBqkv   = cs + COF[15];
  const ushort* cWout   = cs + COF[16];
  const ushort* cBout   = cs + COF[17];
  const ushort* cMw1    = cs + COF[18];
  const ushort* cMb1    = cs + COF[19];
  const ushort* cMw2    = cs + COF[20];
  const ushort* cMb2    = cs + COF[21];
  const ushort* cBn1w   = cs + COF[22];
  const ushort* cBn1b   = cs + COF[23];
  const ushort* cBn2w   = cs + COF[24];
  const ushort* cBn2b   = cs + COF[25];
  const ushort* cBn3w   = cs + COF[26];
  const ushort* cBn3b   = cs + COF[27];

  const ushort* NUL = nullptr;

  // only BN stats need zeroing now (768 floats)
  zero_kernel<<<3, 256, 0, stream>>>((int*)(W + OFF_STATS), 768);

  // ---- canonicalize inputs ----
  CvtArgs ca;
  ca.src[0]  = d_in[2];  ca.src[1]  = d_in[3];  ca.src[2]  = d_in[4];
  ca.src[3]  = d_in[5];  ca.src[4]  = d_in[6];  ca.src[5]  = d_in[7];
  ca.src[6]  = d_in[8];  ca.src[7]  = d_in[9];  ca.src[8]  = d_in[10];
  ca.src[9]  = d_in[11]; ca.src[10] = d_in[12]; ca.src[11] = d_in[13];
  ca.src[12] = d_in[14]; ca.src[13] = d_in[15]; ca.src[14] = d_in[16];
  ca.src[15] = d_in[17]; ca.src[16] = d_in[18]; ca.src[17] = d_in[19];
  ca.src[18] = d_in[20]; ca.src[19] = d_in[21]; ca.src[20] = d_in[22];
  ca.src[21] = d_in[23]; ca.src[22] = d_in[24]; ca.src[23] = d_in[25];
  ca.src[24] = d_in[26]; ca.src[25] = d_in[27]; ca.src[26] = d_in[28];
  ca.src[27] = d_in[29];
  convert_small<<<(CAN_SMALL_TOTAL + 255) / 256, 256, 0, stream>>>(ca, cs, lmraw);
  convert_big<<<(2 * N * C / 4) / 256, 256, 0, stream>>>(d_in[0], d_in[1], canx, canu, lmraw);

  transpose_weights<<<1152, 256, 0, stream>>>(cSpa1, cSpa2, cSpe1, cSpe2,
      cProj, cCheb, cQkv, cWout, cMw1, cMw2, wt);

  // ---- edge prep (LDS-private histograms, no device-scope atomics) ----
  hist_lds<<<2 * HB, 1024, 0, stream>>>(ei, cei, part);
  reduce_cnt<<<N / 256, 256, 0, stream>>>(part, cdt, dis);
  scan_kernel<<<1, 1024, 0, stream>>>(cdt, rp);
  off_kernel<<<N / 256, 256, 0, stream>>>(rp, part, off2);
  edge_scatter<<<HB, 1024, 0, stream>>>(cei, off2, dis, ep);

  dim3 g1(512), g2(1024), g3(1536), bb(256);
  // ---- input MLPs (T0 = x_sp written into Tbig col-block 0) ----
  gemm_lds<128,128,true ,0,true ,false,128,128><<<g1, bb, 0, stream>>>(canx, wt + WT_SPA1, cBspa1, NUL, tmpA);
  gemm_lds<128,128,false,0,true ,false,128,640><<<g1, bb, 0, stream>>>(tmpA, wt + WT_SPA2, cBspa2, NUL, Tbig);
  gemm_lds<128,128,true ,0,true ,false,128,128><<<g1, bb, 0, stream>>>(canx, wt + WT_SPE1, cBspe1, NUL, tmpA);
  gemm_lds<128,128,false,0,true ,false,128,128><<<g1, bb, 0, stream>>>(tmpA, wt + WT_SPE2, cBspe2, NUL, spec);
  gemm_lds<128,128,false,0,false,false,128,128><<<g1, bb, 0, stream>>>(spec, wt + WT_PROJ, NUL,    NUL, hproj);

  // ---- spectral filter M^T ----
  ut_mfma<<<UT_BLOCKS, 256, 0, stream>>>(canu, hproj, parts);
  reduce_mt<<<64, 256, 0, stream>>>(parts, cLambda, cGam, MT);

  // ---- Chebyshev recurrence into Tbig, then one K=640 GEMM -> F1 ----
  spmm_cheb<<<N / 4, 256, 0, stream>>>(rp, ep, Tbig,       NUL,        Tbig + 128, cLmx, 1, 640);
  spmm_cheb<<<N / 4, 256, 0, stream>>>(rp, ep, Tbig + 128, Tbig,       Tbig + 256, cLmx, 0, 640);
  spmm_cheb<<<N / 4, 256, 0, stream>>>(rp, ep, Tbig + 256, Tbig + 128, Tbig + 384, cLmx, 0, 640);
  spmm_cheb<<<N / 4, 256, 0, stream>>>(rp, ep, Tbig + 384, Tbig + 256, Tbig + 512, cLmx, 0, 640);
  gemm_lds<640,128,false,1,true ,false,640,128><<<g1, bb, 0, stream>>>(Tbig, wt + WT_CHEB, cChebB, NUL, F1);

  // ---- out_spectral + x residual; BN1 -> h1 ----
  gemm_lds<128,128,false,2,false,true ,128,128><<<g1, bb, 0, stream>>>(canu, MT, NUL, canx, F1);
  bn_stats<<<256, 256, 0, stream>>>(F1, stats);
  bn_apply<<<(N * C) / 1024, 256, 0, stream>>>(F1, stats, cBn1w, cBn1b, NUL, h1, lmraw, 0);

  // ---- attention branch ----
  gemm_lds<128,384,false,0,true ,false,128,384><<<g3, bb, 0, stream>>>(canx, wt + WT_QKV, cBqkv, NUL, qkvb);
  attn_mfma<<<512, 256, 0, stream>>>(qkvb, attnb);
  gemm_lds<128,128,false,1,true ,true ,128,128><<<g1, bb, 0, stream>>>(attnb, wt + WT_WOUT, cBout, canx, F1);
  bn_stats<<<256, 256, 0, stream>>>(F1, stats + 256);
  bn_apply<<<(N * C) / 1024, 256, 0, stream>>>(F1, stats + 256, cBn2w, cBn2b, h1, comb, lmraw, 0);

  // ---- MLP + final BN ----
  gemm_lds<128,256,true ,0,true ,false,128,256><<<g2, bb, 0, stream>>>(comb, wt + WT_MLP1, cMb1, NUL, mlph);
  gemm_lds<256,128,false,1,true ,true ,256,128><<<g1, bb, 0, stream>>>(mlph, wt + WT_MLP2, cMb2, comb, F1);
  bn_stats<<<256, 256, 0, stream>>>(F1, stats + 512);
  bn_apply<<<(N * C) / 1024, 256, 0, stream>>>(F1, stats + 512, cBn3w, cBn3b, NUL, d_out, lmraw, 1);
}

// Round 2
// 547.595 us; speedup vs baseline: 1.0547x; 1.0083x over previous
//
#include <hip/hip_runtime.h>

typedef short bf16x8 __attribute__((ext_vector_type(8)));
typedef short bf16x4 __attribute__((ext_vector_type(4)));
typedef float f32x4 __attribute__((ext_vector_type(4)));

#define DEVI __device__ __forceinline__

constexpr int N   = 32768;
constexpr int C   = 128;
constexpr int E   = 524288;
constexpr float EPSV = 1e-5f;
constexpr int UT_BLOCKS = 256;
constexpr int HB  = 64;          // histogram blocks per edge-array (src / dst)
constexpr int EPB = E / HB;      // 8192 edges per histogram block

DEVI float bf2f(ushort u){ return __uint_as_float(((uint)u) << 16); }
DEVI ushort f2bf(float f){
  uint u = __float_as_uint(f);
  return (ushort)((u + 0x7fffu + ((u >> 16) & 1u)) >> 16);
}
// packed f32 pair -> bf16 pair (round-to-nearest-even), single HW instr
DEVI uint cvtpk(float lo, float hi){
  uint r;
  asm("v_cvt_pk_bf16_f32 %0, %1, %2" : "=v"(r) : "v"(lo), "v"(hi));
  return r;
}
DEVI float sane(float v){ if (!(v == v)) return 0.f; return fminf(fmaxf(v, -1e30f), 1e30f); }
DEVI bool mode_fp32(const uint* lmraw){ return (lmraw[0] & 0xffffu) == 0u; }

// ---------------- canonical small-input table ----------------
constexpr int CSZ[28] = {128,1,16384,128,16384,128,16384,128,16384,128,81920,128,
                         1,16384,49152,384,16384,128,32768,256,32768,128,
                         128,128,128,128,128,128};
constexpr int COF[28] = {0,128,192,16576,16704,33088,33216,49600,49728,66112,
                         66240,148160,148288,148352,164736,213888,214272,230656,
                         230784,263552,263808,296576,296704,296832,296960,297088,
                         297216,297344};
constexpr int CAN_SMALL_TOTAL = 297472;

struct CvtArgs { const void* src[28]; };

__global__ __launch_bounds__(256) void convert_small(CvtArgs a, ushort* __restrict__ can,
                                                     const uint* __restrict__ lmraw)
{
  bool f32 = mode_fp32(lmraw);
  int idx = blockIdx.x * 256 + threadIdx.x;
  #pragma unroll 1
  for (int s = 0; s < 28; s++) {
    if (idx < CSZ[s]) {
      ushort v = f32 ? f2bf(((const float*)a.src[s])[idx])
                     : ((const ushort*)a.src[s])[idx];
      can[COF[s] + idx] = v;
      return;
    }
    idx -= CSZ[s];
  }
}

__global__ __launch_bounds__(256) void convert_big(const void* __restrict__ xs,
    const void* __restrict__ Us, ushort* __restrict__ canx, ushort* __restrict__ canu,
    const uint* __restrict__ lmraw)
{
  bool f32 = mode_fp32(lmraw);
  size_t e = ((size_t)blockIdx.x * 256 + threadIdx.x) * 4;
  bool isU = e >= (size_t)N * C;
  size_t off = isU ? e - (size_t)N * C : e;
  const void* src = isU ? Us : xs;
  ushort* dst = isU ? canu : canx;
  ushort4 o;
  if (f32) {
    float4 v = *(const float4*)((const float*)src + off);
    o.x = f2bf(v.x); o.y = f2bf(v.y); o.z = f2bf(v.z); o.w = f2bf(v.w);
  } else {
    o = *(const ushort4*)((const ushort*)src + off);
  }
  *(ushort4*)(dst + off) = o;
}

// ---------------- edge prep: LDS-private histograms (no device atomics) ----
__global__ __launch_bounds__(1024) void hist_lds(const int* __restrict__ ei,
    int* __restrict__ cei, ushort* __restrict__ part)
{
  __shared__ uint hist[N / 2];          // 64 KB, two bins per word
  int t = threadIdx.x;
  int b = blockIdx.x;
  bool i64 = ((ei[1] | ei[3] | ei[5] | ei[7]) == 0);
  size_t j0 = (size_t)b * EPB;
  #pragma unroll
  for (int i = t; i < N / 2; i += 1024) hist[i] = 0u;
  __syncthreads();
  for (int k = t; k < EPB; k += 1024) {
    size_t j = j0 + k;
    int v = (i64 ? ei[2 * j] : ei[j]) & (N - 1);
    cei[j] = v;
    atomicAdd(&hist[v >> 1], 1u << ((v & 1) * 16));
  }
  __syncthreads();
  uint* po = (uint*)(part + (size_t)b * N);
  for (int i = t; i < N / 2; i += 1024) po[i] = hist[i];
}

// fold partials: src totals -> dis, dst totals -> cdt
__global__ __launch_bounds__(256) void reduce_cnt(const ushort* __restrict__ part,
    int* __restrict__ cdt, float* __restrict__ dis)
{
  int d = blockIdx.x * 256 + threadIdx.x;
  int s = 0, tt = 0;
  #pragma unroll 8
  for (int b = 0; b < HB; b++) s  += part[(size_t)b * N + d];
  #pragma unroll 8
  for (int b = 0; b < HB; b++) tt += part[(size_t)(HB + b) * N + d];
  cdt[d] = tt;
  dis[d] = s > 0 ? rsqrtf((float)s) : 0.f;
}

__global__ __launch_bounds__(1024) void scan_kernel(const int* __restrict__ cnt,
                                                    int* __restrict__ row_ptr)
{
  __shared__ int sums[1024];
  int t = threadIdx.x;
  int loc[32]; int s = 0;
  int base = t * 32;
  #pragma unroll
  for (int i = 0; i < 32; i++) { loc[i] = s; s += cnt[base + i]; }
  sums[t] = s;
  __syncthreads();
  for (int off = 1; off < 1024; off <<= 1) {
    int v = (t >= off) ? sums[t - off] : 0;
    __syncthreads();
    sums[t] += v;
    __syncthreads();
  }
  int pre = (t == 0) ? 0 : sums[t - 1];
  #pragma unroll
  for (int i = 0; i < 32; i++) row_ptr[base + i] = pre + loc[i];
}

// per-hist-block slot bases: off2[b][d] = rp[d] + sum_{b'<b} partD[b'][d]
__global__ __launch_bounds__(256) void off_kernel(const int* __restrict__ rp,
    const ushort* __restrict__ part, int* __restrict__ off2)
{
  int d = blockIdx.x * 256 + threadIdx.x;
  int run = rp[d];
  #pragma unroll 8
  for (int b = 0; b < HB; b++) {
    off2[(size_t)b * N + d] = run;
    run += part[(size_t)(HB + b) * N + d];
  }
}

// deterministic scatter: block b replays its edge slice, ranks via LDS atomics
__global__ __launch_bounds__(1024) void edge_scatter(const int* __restrict__ cei,
    const int* __restrict__ off2, const float* __restrict__ dis,
    int2* __restrict__ ep)
{
  __shared__ int base[N];               // 128 KB slot cursors
  int t = threadIdx.x;
  int b = blockIdx.x;                   // 0..HB-1
  for (int i = t; i < N; i += 1024) base[i] = off2[(size_t)b * N + i];
  __syncthreads();
  size_t e0 = (size_t)b * EPB;
  for (int k = t; k < EPB; k += 1024) {
    size_t e = e0 + k;
    int s = cei[e], d = cei[e + E];
    int slot = atomicAdd(&base[d], 1);
    int2 v; v.x = s; v.y = __float_as_int(dis[s] * dis[d]);
    ep[slot] = v;
  }
}

// ---------------- weight pre-transpose ----------------
constexpr int WT_SPA1 = 0;
constexpr int WT_SPA2 = 16384;
constexpr int WT_SPE1 = 32768;
constexpr int WT_SPE2 = 49152;
constexpr int WT_PROJ = 65536;
constexpr int WT_CHEB = 81920;    // 128 x 640 (concat layout)
constexpr int WT_QKV  = 163840;   // 384 x 128
constexpr int WT_WOUT = 212992;
constexpr int WT_MLP1 = 229376;   // 256 x 128
constexpr int WT_MLP2 = 262144;   // 128 x 256
constexpr int WT_TOTAL = 294912;

__global__ __launch_bounds__(256) void zero_kernel(int* __restrict__ p, int n)
{
  int i = blockIdx.x * 256 + threadIdx.x;
  if (i < n) p[i] = 0;
}

__global__ __launch_bounds__(256) void transpose_weights(
    const ushort* __restrict__ spa1, const ushort* __restrict__ spa2,
    const ushort* __restrict__ spe1, const ushort* __restrict__ spe2,
    const ushort* __restrict__ proj, const ushort* __restrict__ cheb,
    const ushort* __restrict__ qkv,  const ushort* __restrict__ wout,
    const ushort* __restrict__ mlp1, const ushort* __restrict__ mlp2,
    ushort* __restrict__ wt)
{
  int i = blockIdx.x * 256 + threadIdx.x;
  if (i < 81920) {
    int m = i >> 14, r = i & 16383; int k = r >> 7, n = r & 127;
    const ushort* src = m==0?spa1 : m==1?spa2 : m==2?spe1 : m==3?spe2 : proj;
    wt[m*16384 + n*128 + k] = src[r];
  } else if (i < 163840) {
    int j = i - 81920; int m = j >> 14, r = j & 16383; int k = r >> 7, n = r & 127;
    wt[WT_CHEB + n*640 + m*128 + k] = cheb[j];
  } else if (i < 212992) {
    int j = i - 163840; int k = j / 384, n = j % 384;
    wt[WT_QKV + n*128 + k] = qkv[j];
  } else if (i < 229376) {
    int j = i - 212992; int k = j >> 7, n = j & 127;
    wt[WT_WOUT + n*128 + k] = wout[j];
  } else if (i < 262144) {
    int j = i - 229376; int k = j >> 8, n = j & 255;
    wt[WT_MLP1 + n*128 + k] = mlp1[j];
  } else if (i < WT_TOTAL) {
    int j = i - 262144; int k = j >> 7, n = j & 127;
    wt[WT_MLP2 + n*256 + k] = mlp2[j];
  }
}

// ---------------- LDS-staged MFMA GEMM ----------------
template<int K, int COLS, bool RELU, int OMODE, bool BIAS, bool RES, int ASTR, int OSTR>
__global__ __launch_bounds__(256) void gemm_lds(
    const ushort* __restrict__ A, const ushort* __restrict__ WT,
    const ushort* __restrict__ bias, const ushort* __restrict__ res,
    void* __restrict__ outp)
{
  constexpr int NSEG = COLS / 128;
  constexpr int NKC = K / 128;
  constexpr int BP = 136;
  __shared__ ushort Bs[128 * BP];
  int tid = threadIdx.x;
  int lane = tid & 63, wave = tid >> 6;
  int quad = lane >> 4, l16 = lane & 15;
  int seg = (NSEG > 1) ? (blockIdx.x % NSEG) : 0;
  int rb  = (NSEG > 1) ? (blockIdx.x / NSEG) : blockIdx.x;
  int row0 = rb * 64 + wave * 16;
  const ushort* wseg = WT + (size_t)(seg * 128) * K;

  f32x4 acc[8];
  #pragma unroll
  for (int nt = 0; nt < 8; nt++) acc[nt] = (f32x4){0.f, 0.f, 0.f, 0.f};

  for (int kc = 0; kc < NKC; kc++) {
    if (kc) __syncthreads();
    #pragma unroll
    for (int i = tid; i < 2048; i += 256) {
      int col = i >> 4, ko = (i & 15) * 8;
      *(bf16x8*)&Bs[col * BP + ko] =
          *(const bf16x8*)(wseg + (size_t)col * K + kc * 128 + ko);
    }
    __syncthreads();
    bf16x8 a[4];
    const ushort* ap = A + (size_t)(row0 + l16) * ASTR + kc * 128 + quad * 8;
    #pragma unroll
    for (int kk = 0; kk < 4; kk++) a[kk] = *(const bf16x8*)(ap + kk * 32);
    #pragma unroll
    for (int kk = 0; kk < 4; kk++) {
      #pragma unroll
      for (int nt = 0; nt < 8; nt++) {
        bf16x8 b = *(const bf16x8*)(&Bs[(nt * 16 + l16) * BP + kk * 32 + quad * 8]);
        acc[nt] = __builtin_amdgcn_mfma_f32_16x16x32_bf16(a[kk], b, acc[nt], 0, 0, 0);
      }
    }
  }

  #pragma unroll
  for (int nt = 0; nt < 8; nt++) {
    int col = seg * 128 + nt * 16 + l16;
    float bv = 0.f;
    if (BIAS) bv = bf2f(bias[col]);
    #pragma unroll
    for (int r = 0; r < 4; r++) {
      int row = row0 + quad * 4 + r;
      size_t oi = (size_t)row * OSTR + col;
      float v = acc[nt][r] + bv;
      if (RES) v += bf2f(res[(size_t)row * COLS + col]);
      if (RELU) v = fmaxf(v, 0.f);
      if (OMODE == 0)      ((ushort*)outp)[oi] = f2bf(v);
      else if (OMODE == 1) ((float*)outp)[oi] = v;
      else                 ((float*)outp)[oi] += v;
    }
  }
}

// ---------------- fused lhat / Chebyshev recurrence ----------------
__global__ __launch_bounds__(256) void spmm_cheb(
    const int* __restrict__ row_ptr, const int2* __restrict__ ep,
    const ushort* __restrict__ v,
    const ushort* __restrict__ txprev, ushort* __restrict__ txout,
    const ushort* __restrict__ lambda_max, int first, int str)
{
  int wave = threadIdx.x >> 6, lane = threadIdx.x & 63;
  int sub = lane >> 4, l16 = lane & 15;
  int d = blockIdx.x * 4 + wave;
  float lm = bf2f(lambda_max[0]);
  float scale = 2.f / lm;
  if (!(scale == scale) || fabsf(scale) > 1e6f) scale = 1.f;
  int beg = row_ptr[d];
  int end = (d == N - 1) ? E : row_ptr[d + 1];
  float acc[8] = {0.f,0.f,0.f,0.f,0.f,0.f,0.f,0.f};
  for (int jb = beg; jb < end; jb += 4) {
    int j = jb + sub;
    bool ok = j < end;
    int2 e2 = ep[ok ? j : beg];
    int s = e2.x & (N - 1);
    float w = ok ? __int_as_float(e2.y) : 0.f;
    bf16x8 vv = *(const bf16x8*)(v + (size_t)s * str + l16 * 8);
    #pragma unroll
    for (int i = 0; i < 8; i++) acc[i] += w * bf2f((ushort)vv[i]);
  }
  #pragma unroll
  for (int i = 0; i < 8; i++) {
    acc[i] += __shfl_xor(acc[i], 16);
    acc[i] += __shfl_xor(acc[i], 32);
  }
  if (sub == 0) {
    bf16x8 vd = *(const bf16x8*)(v + (size_t)d * str + l16 * 8);
    bf16x8 tp;
    if (!first) tp = *(const bf16x8*)(txprev + (size_t)d * str + l16 * 8);
    bf16x8 ov;
    #pragma unroll
    for (int i = 0; i < 8; i++) {
      float r = (scale - 1.f) * bf2f((ushort)vd[i]) - scale * acc[i];
      if (!first) r = 2.f * r - bf2f((ushort)tp[i]);
      ov[i] = (short)f2bf(r);
    }
    *(bf16x8*)(txout + (size_t)d * str + l16 * 8) = ov;
  }
}

// ---------------- U^T @ h_proj partials via MFMA ----------------
__global__ __launch_bounds__(256) void ut_mfma(const ushort* __restrict__ U,
    const ushort* __restrict__ hp, float* __restrict__ parts)
{
  constexpr int RP = 40;
  __shared__ ushort Ut[128 * RP];
  __shared__ ushort Ht[128 * RP];
  int t = threadIdx.x;
  int lane = t & 63, wave = t >> 6;
  int quad = lane >> 4, l16 = lane & 15;

  f32x4 acc[2][8];
  #pragma unroll
  for (int a = 0; a < 2; a++)
    #pragma unroll
    for (int ct = 0; ct < 8; ct++) acc[a][ct] = (f32x4){0.f, 0.f, 0.f, 0.f};

  for (int ch = 0; ch < 4; ch++) {
    int n0 = blockIdx.x * 128 + ch * 32;
    __syncthreads();
    for (int i = t; i < 2048; i += 256) {
      int r2 = i >> 7, c = i & 127;
      uint u0 = U [(size_t)(n0 + r2 * 2) * 128 + c];
      uint u1 = U [(size_t)(n0 + r2 * 2 + 1) * 128 + c];
      *(uint*)&Ut[c * RP + r2 * 2] = (u0 & 0xffffu) | (u1 << 16);
      uint h0 = hp[(size_t)(n0 + r2 * 2) * 128 + c];
      uint h1 = hp[(size_t)(n0 + r2 * 2 + 1) * 128 + c];
      *(uint*)&Ht[c * RP + r2 * 2] = (h0 & 0xffffu) | (h1 << 16);
    }
    __syncthreads();
    bf16x8 bfr[8];
    #pragma unroll
    for (int ct = 0; ct < 8; ct++)
      bfr[ct] = *(const bf16x8*)(&Ht[(ct * 16 + l16) * RP + quad * 8]);
    #pragma unroll
    for (int a = 0; a < 2; a++) {
      int kt = wave * 2 + a;
      bf16x8 af = *(const bf16x8*)(&Ut[(kt * 16 + l16) * RP + quad * 8]);
      #pragma unroll
      for (int ct = 0; ct < 8; ct++)
        acc[a][ct] = __builtin_amdgcn_mfma_f32_16x16x32_bf16(af, bfr[ct], acc[a][ct], 0, 0, 0);
    }
  }

  float* po = parts + (size_t)blockIdx.x * 16384;
  #pragma unroll
  for (int a = 0; a < 2; a++) {
    int kt = wave * 2 + a;
    #pragma unroll
    for (int ct = 0; ct < 8; ct++)
      #pragma unroll
      for (int r = 0; r < 4; r++)
        po[(kt * 16 + quad * 4 + r) * 128 + ct * 16 + l16] = acc[a][ct][r];
  }
}

__global__ __launch_bounds__(256) void reduce_mt(const float* __restrict__ parts,
    const ushort* __restrict__ Lambda, const ushort* __restrict__ gamma,
    ushort* __restrict__ MT)
{
  int e = blockIdx.x * 256 + threadIdx.x;
  int keig = e >> 7, c = e & 127;
  float s = 0.f;
  for (int p = 0; p < UT_BLOCKS; p++) s += parts[(size_t)p * 16384 + e];
  float g = bf2f(gamma[0]);
  float lam = bf2f(Lambda[keig]);
  float sl = __expf(-g * lam * lam);
  MT[c * 128 + keig] = f2bf(sl * s);
}

// ---------------- BatchNorm ----------------
__global__ __launch_bounds__(256) void bn_stats(const float* __restrict__ h,
                                                float* __restrict__ stats)
{
  int c = threadIdx.x & 127, half = threadIdx.x >> 7;
  int r0 = blockIdx.x * 128 + half;
  float s = 0.f, s2 = 0.f;
  for (int i = 0; i < 64; i++) {
    float v = sane(h[(size_t)(r0 + i * 2) * 128 + c]);
    s += v; s2 += v * v;
  }
  atomicAdd(&stats[c], s);
  atomicAdd(&stats[128 + c], s2);
}

__global__ __launch_bounds__(256) void bn_apply(const float* __restrict__ h,
    const float* __restrict__ st, const ushort* __restrict__ gw,
    const ushort* __restrict__ gb, const ushort* __restrict__ add,
    void* __restrict__ out, const uint* __restrict__ lmraw, int final_out)
{
  size_t e = ((size_t)blockIdx.x * 256 + threadIdx.x) * 4;
  int c0 = (int)(e & 127);
  float4 hv = *(const float4*)(h + e);
  float xv[4] = {sane(hv.x), sane(hv.y), sane(hv.z), sane(hv.w)};
  float addv[4] = {0.f, 0.f, 0.f, 0.f};
  if (add) {
    ushort4 av = *(const ushort4*)(add + e);
    addv[0] = bf2f(av.x); addv[1] = bf2f(av.y);
    addv[2] = bf2f(av.z); addv[3] = bf2f(av.w);
  }
  float r[4];
  #pragma unroll
  for (int j = 0; j < 4; j++) {
    int c = c0 + j;
    float mu = st[c] * (1.f / 32768.f);
    float var = fmaxf(st[128 + c] * (1.f / 32768.f) - mu * mu, 0.f);
    r[j] = (xv[j] - mu) * rsqrtf(var + EPSV) * bf2f(gw[c]) + bf2f(gb[c]) + addv[j];
  }
  if (final_out && mode_fp32(lmraw)) {
    float4 o4; o4.x = r[0]; o4.y = r[1]; o4.z = r[2]; o4.w = r[3];
    *(float4*)((float*)out + e) = o4;
  } else {
    ushort4 o;
    o.x = f2bf(r[0]); o.y = f2bf(r[1]); o.z = f2bf(r[2]); o.w = f2bf(r[3]);
    *(ushort4*)((ushort*)out + e) = o;
  }
}

// ---------------- MFMA flash attention ----------------
// 512 blocks: (graph g, head hh, q-half). K and V staged in LDS; softmax P
// packed via v_cvt_pk_bf16_f32; PV batches 2 key-tiles per MFMA (full K=32).
__global__ __launch_bounds__(256) void attn_mfma(const ushort* __restrict__ qkv,
                                                 ushort* __restrict__ attn)
{
  constexpr int VP = 516;            // 258 words = 2 mod 32 -> conflict-free b64
  constexpr int KP = 40;             // 20 words -> uniform bank spread on b128
  __shared__ ushort Kt[512 * KP];    // 40 KB  [key][dim]
  __shared__ ushort Vt[32 * VP];     // 33 KB  [dim][key]
  int b = blockIdx.x;
  int g = b >> 3, hh = (b >> 1) & 3, half = b & 1;
  int lane = threadIdx.x & 63, wave = threadIdx.x >> 6;
  int quad = lane >> 4, l16 = lane & 15;
  const ushort* base = qkv + (size_t)g * 512 * 384;

  // stage K: one 16B fragment per (key, 8-dim chunk)
  for (int i = threadIdx.x; i < 512 * 4; i += 256) {
    int key = i >> 2, c8 = (i & 3) * 8;
    *(bf16x8*)&Kt[key * KP + c8] =
        *(const bf16x8*)(base + (size_t)key * 384 + 128 + hh * 32 + c8);
  }
  // stage V transposed, key-pairs packed as one b32 write
  for (int i = threadIdx.x; i < 256 * 8; i += 256) {
    int kp = i >> 3, d4 = (i & 7) * 4;
    const ushort* va = base + (size_t)(2 * kp) * 384 + 256 + hh * 32 + d4;
    ushort4 a = *(const ushort4*)va;
    ushort4 c = *(const ushort4*)(va + 384);
    *(uint*)&Vt[(d4 + 0) * VP + 2 * kp] = (uint)a.x | ((uint)c.x << 16);
    *(uint*)&Vt[(d4 + 1) * VP + 2 * kp] = (uint)a.y | ((uint)c.y << 16);
    *(uint*)&Vt[(d4 + 2) * VP + 2 * kp] = (uint)a.z | ((uint)c.z << 16);
    *(uint*)&Vt[(d4 + 3) * VP + 2 * kp] = (uint)a.w | ((uint)c.w << 16);
  }
  __syncthreads();

  int q0 = half * 256 + wave * 64;
  bf16x8 qf[4];
  #pragma unroll
  for (int i = 0; i < 4; i++)
    qf[i] = *(const bf16x8*)(base + (size_t)(q0 + i * 16 + l16) * 384 + hh * 32 + quad * 8);

  f32x4 O[2][4];
  #pragma unroll
  for (int dt = 0; dt < 2; dt++)
    #pragma unroll
    for (int i = 0; i < 4; i++) O[dt][i] = (f32x4){0.f, 0.f, 0.f, 0.f};
  float lsum[4] = {0.f, 0.f, 0.f, 0.f};
  const float SC2 = 0.17677669529663687f * 1.4426950408889634f; // /sqrt(dh)*log2e

  union PU { uint u[4]; bf16x8 v; };
  union VU { uint2 a[2]; bf16x8 v; };

  for (int kt2 = 0; kt2 < 16; kt2++) {
    int k0 = kt2 * 32;
    bf16x8 kfA = *(const bf16x8*)&Kt[(k0 + l16) * KP + quad * 8];
    bf16x8 kfB = *(const bf16x8*)&Kt[(k0 + 16 + l16) * KP + quad * 8];
    PU pw[4];
    #pragma unroll
    for (int i = 0; i < 4; i++) {
      f32x4 sA = __builtin_amdgcn_mfma_f32_16x16x32_bf16(kfA, qf[i], (f32x4){0.f,0.f,0.f,0.f}, 0, 0, 0);
      f32x4 sB = __builtin_amdgcn_mfma_f32_16x16x32_bf16(kfB, qf[i], (f32x4){0.f,0.f,0.f,0.f}, 0, 0, 0);
      float p0 = exp2f(fminf(sA[0] * SC2, 86.5f));
      float p1 = exp2f(fminf(sA[1] * SC2, 86.5f));
      float p2 = exp2f(fminf(sA[2] * SC2, 86.5f));
      float p3 = exp2f(fminf(sA[3] * SC2, 86.5f));
      float p4 = exp2f(fminf(sB[0] * SC2, 86.5f));
      float p5 = exp2f(fminf(sB[1] * SC2, 86.5f));
      float p6 = exp2f(fminf(sB[2] * SC2, 86.5f));
      float p7 = exp2f(fminf(sB[3] * SC2, 86.5f));
      lsum[i] += ((p0 + p1) + (p2 + p3)) + ((p4 + p5) + (p6 + p7));
      pw[i].u[0] = cvtpk(p0, p1); pw[i].u[1] = cvtpk(p2, p3);
      pw[i].u[2] = cvtpk(p4, p5); pw[i].u[3] = cvtpk(p6, p7);
    }
    #pragma unroll
    for (int dt = 0; dt < 2; dt++) {
      int drow = (dt * 16 + l16) * VP;
      VU vu;
      vu.a[0] = *(const uint2*)&Vt[drow + k0 + quad * 4];
      vu.a[1] = *(const uint2*)&Vt[drow + k0 + 16 + quad * 4];
      #pragma unroll
      for (int i = 0; i < 4; i++)
        O[dt][i] = __builtin_amdgcn_mfma_f32_16x16x32_bf16(vu.v, pw[i].v, O[dt][i], 0, 0, 0);
    }
  }

  #pragma unroll
  for (int i = 0; i < 4; i++) {
    float l = lsum[i];
    l += __shfl_xor(l, 16);
    l += __shfl_xor(l, 32);
    lsum[i] = 1.f / l;
  }

  #pragma unroll
  for (int i = 0; i < 4; i++) {
    size_t node = (size_t)g * 512 + q0 + i * 16 + l16;
    #pragma unroll
    for (int dt = 0; dt < 2; dt++) {
      uint2 o;
      o.x = cvtpk(O[dt][i][0] * lsum[i], O[dt][i][1] * lsum[i]);
      o.y = cvtpk(O[dt][i][2] * lsum[i], O[dt][i][3] * lsum[i]);
      *(uint2*)(attn + node * 128 + hh * 32 + dt * 16 + quad * 4) = o;
    }
  }
}

// ---------------- workspace layout (bytes), total 103 MB ----------------
constexpr size_t KB = 1024;
constexpr size_t MB = 1048576;
constexpr size_t OFF_WT    = 0;                 // 576 KB
constexpr size_t OFF_CDT   = 576 * KB;          // 128 KB (cnt_dst totals)
constexpr size_t OFF_RP    = 704 * KB;          // 128 KB
constexpr size_t OFF_DIS   = 832 * KB;          // 128 KB
constexpr size_t OFF_MT    = 960 * KB;          // 32 KB
constexpr size_t OFF_STATS = 1024 * KB;         // 3 KB  [zeroed]
constexpr size_t OFF_CEI   = 6  * MB;           // 4 MB
constexpr size_t OFF_EP    = 10 * MB;           // 4 MB (packed int2 per slot)
constexpr size_t OFF_CANX  = 14 * MB;           // 8 MB; later comb
constexpr size_t OFF_CANU  = 22 * MB;           // 8 MB; later h1
constexpr size_t OFF_CANS  = 30 * MB;           // ~0.6 MB
constexpr size_t OFF_F1    = 31 * MB;           // fp32 16 MB (spec shares, dead before F1)
constexpr size_t OFF_SPEC  = 31 * MB;           // 8 MB
constexpr size_t OFF_HPROJ = 39 * MB;           // 8 MB (tmpA shares; dead before F1 write)
constexpr size_t OFF_TBIG  = 47 * MB;           // 40 MB; later qkv/mlph
constexpr size_t OFF_PARTH = OFF_TBIG;          // 8 MB hist partials (dead before Tbig)
constexpr size_t OFF_OFF2  = OFF_TBIG + 8 * MB; // 8 MB per-block slot bases
constexpr size_t OFF_PARTS = 87 * MB;           // 16 MB; attnb shares; end 103 MB

extern "C" void kernel_launch(void* const* d_in, const int* in_sizes, int n_in,
                              void* d_out, int out_size, void* d_ws, size_t ws_size,
                              hipStream_t stream) {
  (void)in_sizes; (void)n_in; (void)out_size; (void)ws_size;
  const uint* lmraw = (const uint*)d_in[3];
  const int*  ei    = (const int*)d_in[30];

  char* W = (char*)d_ws;
  ushort* wt    = (ushort*)(W + OFF_WT);
  int*    cdt   = (int*)(W + OFF_CDT);
  int*    rp    = (int*)(W + OFF_RP);
  float*  dis   = (float*)(W + OFF_DIS);
  ushort* MT    = (ushort*)(W + OFF_MT);
  float*  stats = (float*)(W + OFF_STATS);
  int*    cei   = (int*)(W + OFF_CEI);
  int2*   ep    = (int2*)(W + OFF_EP);
  ushort* part  = (ushort*)(W + OFF_PARTH);
  int*    off2  = (int*)(W + OFF_OFF2);
  ushort* canx  = (ushort*)(W + OFF_CANX);
  ushort* canu  = (ushort*)(W + OFF_CANU);
  ushort* cs    = (ushort*)(W + OFF_CANS);
  float*  F1    = (float*)(W + OFF_F1);
  ushort* spec  = (ushort*)(W + OFF_SPEC);
  ushort* tmpA  = (ushort*)(W + OFF_HPROJ);
  ushort* hproj = (ushort*)(W + OFF_HPROJ);
  ushort* Tbig  = (ushort*)(W + OFF_TBIG);
  ushort* qkvb  = (ushort*)(W + OFF_TBIG);
  ushort* mlph  = (ushort*)(W + OFF_TBIG);
  float*  parts = (float*)(W + OFF_PARTS);
  ushort* attnb = (ushort*)(W + OFF_PARTS);
  ushort* h1    = (ushort*)(W + OFF_CANU);
  ushort* comb  = (ushort*)(W + OFF_CANX);

  const ushort* cLambda = cs + COF[0];
  const ushort* cLmx    = cs + COF[1];
  const ushort* cSpa1   = cs + COF[2];
  const ushort* cBspa1  = cs + COF[3];
  const ushort* cSpa2   = cs + COF[4];
  const ushort* cBspa2  = cs + COF[5];
  const ushort* cSpe1   = cs + COF[6];
  const ushort* cBspe1  = cs + COF[7];
  const ushort* cSpe2   = cs + COF[8];
  const ushort* cBspe2  = cs + COF[9];
  const ushort* cCheb   = cs + COF[10];
  const ushort* cChebB  = cs + COF[11];
  const ushort* cGam    = cs + COF[12];
  const ushort* cProj   = cs + COF[13];
  const ushort* cQkv    = cs + COF[14];
  const ushort* cBqkv   = cs + COF[15];
  const ushort* cWout   = cs + COF[16];
  const ushort* cBout   = cs + COF[17];
  const ushort* cMw1    = cs + COF[18];
  const ushort* cMb1    = cs + COF[19];
  const ushort* cMw2    = cs + COF[20];
  const ushort* cMb2    = cs + COF[21];
  const ushort* cBn1w   = cs + COF[22];
  const ushort* cBn1b   = cs + COF[23];
  const ushort* cBn2w   = cs + COF[24];
  const ushort* cBn2b   = cs + COF[25];
  const ushort* cBn3w   = cs + COF[26];
  const ushort* cBn3b   = cs + COF[27];

  const ushort* NUL = nullptr;

  // only BN stats need zeroing now (768 floats)
  zero_kernel<<<3, 256, 0, stream>>>((int*)(W + OFF_STATS), 768);

  // ---- canonicalize inputs ----
  CvtArgs ca;
  ca.src[0]  = d_in[2];  ca.src[1]  = d_in[3];  ca.src[2]  = d_in[4];
  ca.src[3]  = d_in[5];  ca.src[4]  = d_in[6];  ca.src[5]  = d_in[7];
  ca.src[6]  = d_in[8];  ca.src[7]  = d_in[9];  ca.src[8]  = d_in[10];
  ca.src[9]  = d_in[11]; ca.src[10] = d_in[12]; ca.src[11] = d_in[13];
  ca.src[12] = d_in[14]; ca.src[13] = d_in[15]; ca.src[14] = d_in[16];
  ca.src[15] = d_in[17]; ca.src[16] = d_in[18]; ca.src[17] = d_in[19];
  ca.src[18] = d_in[20]; ca.src[19] = d_in[21]; ca.src[20] = d_in[22];
  ca.src[21] = d_in[23]; ca.src[22] = d_in[24]; ca.src[23] = d_in[25];
  ca.src[24] = d_in[26]; ca.src[25] = d_in[27]; ca.src[26] = d_in[28];
  ca.src[27] = d_in[29];
  convert_small<<<(CAN_SMALL_TOTAL + 255) / 256, 256, 0, stream>>>(ca, cs, lmraw);
  convert_big<<<(2 * N * C / 4) / 256, 256, 0, stream>>>(d_in[0], d_in[1], canx, canu, lmraw);

  transpose_weights<<<1152, 256, 0, stream>>>(cSpa1, cSpa2, cSpe1, cSpe2,
      cProj, cCheb, cQkv, cWout, cMw1, cMw2, wt);

  // ---- edge prep (LDS-private histograms, no device-scope atomics) ----
  hist_lds<<<2 * HB, 1024, 0, stream>>>(ei, cei, part);
  reduce_cnt<<<N / 256, 256, 0, stream>>>(part, cdt, dis);
  scan_kernel<<<1, 1024, 0, stream>>>(cdt, rp);
  off_kernel<<<N / 256, 256, 0, stream>>>(rp, part, off2);
  edge_scatter<<<HB, 1024, 0, stream>>>(cei, off2, dis, ep);

  dim3 g1(512), g2(1024), g3(1536), bb(256);
  // ---- input MLPs (T0 = x_sp written into Tbig col-block 0) ----
  gemm_lds<128,128,true ,0,true ,false,128,128><<<g1, bb, 0, stream>>>(canx, wt + WT_SPA1, cBspa1, NUL, tmpA);
  gemm_lds<128,128,false,0,true ,false,128,640><<<g1, bb, 0, stream>>>(tmpA, wt + WT_SPA2, cBspa2, NUL, Tbig);
  gemm_lds<128,128,true ,0,true ,false,128,128><<<g1, bb, 0, stream>>>(canx, wt + WT_SPE1, cBspe1, NUL, tmpA);
  gemm_lds<128,128,false,0,true ,false,128,128><<<g1, bb, 0, stream>>>(tmpA, wt + WT_SPE2, cBspe2, NUL, spec);
  gemm_lds<128,128,false,0,false,false,128,128><<<g1, bb, 0, stream>>>(spec, wt + WT_PROJ, NUL,    NUL, hproj);

  // ---- spectral filter M^T ----
  ut_mfma<<<UT_BLOCKS, 256, 0, stream>>>(canu, hproj, parts);
  reduce_mt<<<64, 256, 0, stream>>>(parts, cLambda, cGam, MT);

  // ---- Chebyshev recurrence into Tbig, then one K=640 GEMM -> F1 ----
  spmm_cheb<<<N / 4, 256, 0, stream>>>(rp, ep, Tbig,       NUL,        Tbig + 128, cLmx, 1, 640);
  spmm_cheb<<<N / 4, 256, 0, stream>>>(rp, ep, Tbig + 128, Tbig,       Tbig + 256, cLmx, 0, 640);
  spmm_cheb<<<N / 4, 256, 0, stream>>>(rp, ep, Tbig + 256, Tbig + 128, Tbig + 384, cLmx, 0, 640);
  spmm_cheb<<<N / 4, 256, 0, stream>>>(rp, ep, Tbig + 384, Tbig + 256, Tbig + 512, cLmx, 0, 640);
  gemm_lds<640,128,false,1,true ,false,640,128><<<g1, bb, 0, stream>>>(Tbig, wt + WT_CHEB, cChebB, NUL, F1);

  // ---- out_spectral + x residual; BN1 -> h1 ----
  gemm_lds<128,128,false,2,false,true ,128,128><<<g1, bb, 0, stream>>>(canu, MT, NUL, canx, F1);
  bn_stats<<<256, 256, 0, stream>>>(F1, stats);
  bn_apply<<<(N * C) / 1024, 256, 0, stream>>>(F1, stats, cBn1w, cBn1b, NUL, h1, lmraw, 0);

  // ---- attention branch ----
  gemm_lds<128,384,false,0,true ,false,128,384><<<g3, bb, 0, stream>>>(canx, wt + WT_QKV, cBqkv, NUL, qkvb);
  attn_mfma<<<512, 256, 0, stream>>>(qkvb, attnb);
  gemm_lds<128,128,false,1,true ,true ,128,128><<<g1, bb, 0, stream>>>(attnb, wt + WT_WOUT, cBout, canx, F1);
  bn_stats<<<256, 256, 0, stream>>>(F1, stats + 256);
  bn_apply<<<(N * C) / 1024, 256, 0, stream>>>(F1, stats + 256, cBn2w, cBn2b, h1, comb, lmraw, 0);

  // ---- MLP + final BN ----
  gemm_lds<128,256,true ,0,true ,false,128,256><<<g2, bb, 0, stream>>>(comb, wt + WT_MLP1, cMb1, NUL, mlph);
  gemm_lds<256,128,false,1,true ,true ,256,128><<<g1, bb, 0, stream>>>(mlph, wt + WT_MLP2, cMb2, comb, F1);
  bn_stats<<<256, 256, 0, stream>>>(F1, stats + 512);
  bn_apply<<<(N * C) / 1024, 256, 0, stream>>>(F1, stats + 512, cBn3w, cBn3b, NUL, d_out, lmraw, 1);
}

// Round 3
// 540.887 us; speedup vs baseline: 1.0678x; 1.0124x over previous
//
#include <hip/hip_runtime.h>

typedef short bf16x8 __attribute__((ext_vector_type(8)));
typedef short bf16x4 __attribute__((ext_vector_type(4)));
typedef float f32x4 __attribute__((ext_vector_type(4)));

#define DEVI __device__ __forceinline__

constexpr int N   = 32768;
constexpr int C   = 128;
constexpr int E   = 524288;
constexpr float EPSV = 1e-5f;
constexpr int UT_BLOCKS = 256;
constexpr int HB  = 64;          // histogram blocks per edge-array (src / dst)
constexpr int EPB = E / HB;      // 8192 edges per histogram block
// softmax scale folded into Q at QKV-GEMM epilogue: 1/sqrt(32) * log2(e)
constexpr float QSCALE = 0.17677669529663687f * 1.4426950408889634f;

DEVI float bf2f(ushort u){ return __uint_as_float(((uint)u) << 16); }
DEVI ushort f2bf(float f){
  uint u = __float_as_uint(f);
  return (ushort)((u + 0x7fffu + ((u >> 16) & 1u)) >> 16);
}
// packed f32 pair -> bf16 pair (round-to-nearest-even), single HW instr
DEVI uint cvtpk(float lo, float hi){
  uint r;
  asm("v_cvt_pk_bf16_f32 %0, %1, %2" : "=v"(r) : "v"(lo), "v"(hi));
  return r;
}
// single-instruction 2^x (no libm edge-case code)
DEVI float fexp2(float x){
  float r;
  asm("v_exp_f32 %0, %1" : "=v"(r) : "v"(x));
  return r;
}
DEVI float sane(float v){ if (!(v == v)) return 0.f; return fminf(fmaxf(v, -1e30f), 1e30f); }
DEVI bool mode_fp32(const uint* lmraw){ return (lmraw[0] & 0xffffu) == 0u; }

// ---------------- canonical small-input table ----------------
constexpr int CSZ[28] = {128,1,16384,128,16384,128,16384,128,16384,128,81920,128,
                         1,16384,49152,384,16384,128,32768,256,32768,128,
                         128,128,128,128,128,128};
constexpr int COF[28] = {0,128,192,16576,16704,33088,33216,49600,49728,66112,
                         66240,148160,148288,148352,164736,213888,214272,230656,
                         230784,263552,263808,296576,296704,296832,296960,297088,
                         297216,297344};
constexpr int CAN_SMALL_TOTAL = 297472;

struct CvtArgs { const void* src[28]; };

__global__ __launch_bounds__(256) void convert_small(CvtArgs a, ushort* __restrict__ can,
                                                     const uint* __restrict__ lmraw)
{
  bool f32 = mode_fp32(lmraw);
  int idx = blockIdx.x * 256 + threadIdx.x;
  #pragma unroll 1
  for (int s = 0; s < 28; s++) {
    if (idx < CSZ[s]) {
      ushort v = f32 ? f2bf(((const float*)a.src[s])[idx])
                     : ((const ushort*)a.src[s])[idx];
      can[COF[s] + idx] = v;
      return;
    }
    idx -= CSZ[s];
  }
}

__global__ __launch_bounds__(256) void convert_big(const void* __restrict__ xs,
    const void* __restrict__ Us, ushort* __restrict__ canx, ushort* __restrict__ canu,
    const uint* __restrict__ lmraw)
{
  bool f32 = mode_fp32(lmraw);
  size_t e = ((size_t)blockIdx.x * 256 + threadIdx.x) * 4;
  bool isU = e >= (size_t)N * C;
  size_t off = isU ? e - (size_t)N * C : e;
  const void* src = isU ? Us : xs;
  ushort* dst = isU ? canu : canx;
  ushort4 o;
  if (f32) {
    float4 v = *(const float4*)((const float*)src + off);
    o.x = f2bf(v.x); o.y = f2bf(v.y); o.z = f2bf(v.z); o.w = f2bf(v.w);
  } else {
    o = *(const ushort4*)((const ushort*)src + off);
  }
  *(ushort4*)(dst + off) = o;
}

// ---------------- edge prep: LDS-private histograms (no device atomics) ----
__global__ __launch_bounds__(1024) void hist_lds(const int* __restrict__ ei,
    int* __restrict__ cei, ushort* __restrict__ part)
{
  __shared__ uint hist[N / 2];          // 64 KB, two bins per word
  int t = threadIdx.x;
  int b = blockIdx.x;
  bool i64 = ((ei[1] | ei[3] | ei[5] | ei[7]) == 0);
  size_t j0 = (size_t)b * EPB;
  #pragma unroll
  for (int i = t; i < N / 2; i += 1024) hist[i] = 0u;
  __syncthreads();
  for (int k = t; k < EPB; k += 1024) {
    size_t j = j0 + k;
    int v = (i64 ? ei[2 * j] : ei[j]) & (N - 1);
    cei[j] = v;
    atomicAdd(&hist[v >> 1], 1u << ((v & 1) * 16));
  }
  __syncthreads();
  uint* po = (uint*)(part + (size_t)b * N);
  for (int i = t; i < N / 2; i += 1024) po[i] = hist[i];
}

// fold partials: src totals -> dis, dst totals -> cdt
__global__ __launch_bounds__(256) void reduce_cnt(const ushort* __restrict__ part,
    int* __restrict__ cdt, float* __restrict__ dis)
{
  int d = blockIdx.x * 256 + threadIdx.x;
  int s = 0, tt = 0;
  #pragma unroll 8
  for (int b = 0; b < HB; b++) s  += part[(size_t)b * N + d];
  #pragma unroll 8
  for (int b = 0; b < HB; b++) tt += part[(size_t)(HB + b) * N + d];
  cdt[d] = tt;
  dis[d] = s > 0 ? rsqrtf((float)s) : 0.f;
}

__global__ __launch_bounds__(1024) void scan_kernel(const int* __restrict__ cnt,
                                                    int* __restrict__ row_ptr)
{
  __shared__ int sums[1024];
  int t = threadIdx.x;
  int loc[32]; int s = 0;
  int base = t * 32;
  #pragma unroll
  for (int i = 0; i < 32; i++) { loc[i] = s; s += cnt[base + i]; }
  sums[t] = s;
  __syncthreads();
  for (int off = 1; off < 1024; off <<= 1) {
    int v = (t >= off) ? sums[t - off] : 0;
    __syncthreads();
    sums[t] += v;
    __syncthreads();
  }
  int pre = (t == 0) ? 0 : sums[t - 1];
  #pragma unroll
  for (int i = 0; i < 32; i++) row_ptr[base + i] = pre + loc[i];
}

// per-hist-block slot bases: off2[b][d] = rp[d] + sum_{b'<b} partD[b'][d]
__global__ __launch_bounds__(256) void off_kernel(const int* __restrict__ rp,
    const ushort* __restrict__ part, int* __restrict__ off2)
{
  int d = blockIdx.x * 256 + threadIdx.x;
  int run = rp[d];
  #pragma unroll 8
  for (int b = 0; b < HB; b++) {
    off2[(size_t)b * N + d] = run;
    run += part[(size_t)(HB + b) * N + d];
  }
}

// deterministic scatter: block b replays its edge slice, ranks via LDS atomics
__global__ __launch_bounds__(1024) void edge_scatter(const int* __restrict__ cei,
    const int* __restrict__ off2, const float* __restrict__ dis,
    int2* __restrict__ ep)
{
  __shared__ int base[N];               // 128 KB slot cursors
  int t = threadIdx.x;
  int b = blockIdx.x;                   // 0..HB-1
  for (int i = t; i < N; i += 1024) base[i] = off2[(size_t)b * N + i];
  __syncthreads();
  size_t e0 = (size_t)b * EPB;
  for (int k = t; k < EPB; k += 1024) {
    size_t e = e0 + k;
    int s = cei[e], d = cei[e + E];
    int slot = atomicAdd(&base[d], 1);
    int2 v; v.x = s; v.y = __float_as_int(dis[s] * dis[d]);
    ep[slot] = v;
  }
}

// ---------------- weight pre-transpose ----------------
constexpr int WT_SPA1 = 0;
constexpr int WT_SPA2 = 16384;
constexpr int WT_SPE1 = 32768;
constexpr int WT_SPE2 = 49152;
constexpr int WT_PROJ = 65536;
constexpr int WT_CHEB = 81920;    // 128 x 640 (concat layout)
constexpr int WT_QKV  = 163840;   // 384 x 128
constexpr int WT_WOUT = 212992;
constexpr int WT_MLP1 = 229376;   // 256 x 128
constexpr int WT_MLP2 = 262144;   // 128 x 256
constexpr int WT_TOTAL = 294912;

__global__ __launch_bounds__(256) void zero_kernel(int* __restrict__ p, int n)
{
  int i = blockIdx.x * 256 + threadIdx.x;
  if (i < n) p[i] = 0;
}

__global__ __launch_bounds__(256) void transpose_weights(
    const ushort* __restrict__ spa1, const ushort* __restrict__ spa2,
    const ushort* __restrict__ spe1, const ushort* __restrict__ spe2,
    const ushort* __restrict__ proj, const ushort* __restrict__ cheb,
    const ushort* __restrict__ qkv,  const ushort* __restrict__ wout,
    const ushort* __restrict__ mlp1, const ushort* __restrict__ mlp2,
    ushort* __restrict__ wt)
{
  int i = blockIdx.x * 256 + threadIdx.x;
  if (i < 81920) {
    int m = i >> 14, r = i & 16383; int k = r >> 7, n = r & 127;
    const ushort* src = m==0?spa1 : m==1?spa2 : m==2?spe1 : m==3?spe2 : proj;
    wt[m*16384 + n*128 + k] = src[r];
  } else if (i < 163840) {
    int j = i - 81920; int m = j >> 14, r = j & 16383; int k = r >> 7, n = r & 127;
    wt[WT_CHEB + n*640 + m*128 + k] = cheb[j];
  } else if (i < 212992) {
    int j = i - 163840; int k = j / 384, n = j % 384;
    wt[WT_QKV + n*128 + k] = qkv[j];
  } else if (i < 229376) {
    int j = i - 212992; int k = j >> 7, n = j & 127;
    wt[WT_WOUT + n*128 + k] = wout[j];
  } else if (i < 262144) {
    int j = i - 229376; int k = j >> 8, n = j & 255;
    wt[WT_MLP1 + n*128 + k] = mlp1[j];
  } else if (i < WT_TOTAL) {
    int j = i - 262144; int k = j >> 7, n = j & 127;
    wt[WT_MLP2 + n*256 + k] = mlp2[j];
  }
}

// ---------------- LDS-staged MFMA GEMM ----------------
template<int K, int COLS, bool RELU, int OMODE, bool BIAS, bool RES, int ASTR, int OSTR, bool QSC>
__global__ __launch_bounds__(256) void gemm_lds(
    const ushort* __restrict__ A, const ushort* __restrict__ WT,
    const ushort* __restrict__ bias, const ushort* __restrict__ res,
    void* __restrict__ outp)
{
  constexpr int NSEG = COLS / 128;
  constexpr int NKC = K / 128;
  constexpr int BP = 136;
  __shared__ ushort Bs[128 * BP];
  int tid = threadIdx.x;
  int lane = tid & 63, wave = tid >> 6;
  int quad = lane >> 4, l16 = lane & 15;
  int seg = (NSEG > 1) ? (blockIdx.x % NSEG) : 0;
  int rb  = (NSEG > 1) ? (blockIdx.x / NSEG) : blockIdx.x;
  int row0 = rb * 64 + wave * 16;
  const ushort* wseg = WT + (size_t)(seg * 128) * K;

  f32x4 acc[8];
  #pragma unroll
  for (int nt = 0; nt < 8; nt++) acc[nt] = (f32x4){0.f, 0.f, 0.f, 0.f};

  for (int kc = 0; kc < NKC; kc++) {
    if (kc) __syncthreads();
    #pragma unroll
    for (int i = tid; i < 2048; i += 256) {
      int col = i >> 4, ko = (i & 15) * 8;
      *(bf16x8*)&Bs[col * BP + ko] =
          *(const bf16x8*)(wseg + (size_t)col * K + kc * 128 + ko);
    }
    __syncthreads();
    bf16x8 a[4];
    const ushort* ap = A + (size_t)(row0 + l16) * ASTR + kc * 128 + quad * 8;
    #pragma unroll
    for (int kk = 0; kk < 4; kk++) a[kk] = *(const bf16x8*)(ap + kk * 32);
    #pragma unroll
    for (int kk = 0; kk < 4; kk++) {
      #pragma unroll
      for (int nt = 0; nt < 8; nt++) {
        bf16x8 b = *(const bf16x8*)(&Bs[(nt * 16 + l16) * BP + kk * 32 + quad * 8]);
        acc[nt] = __builtin_amdgcn_mfma_f32_16x16x32_bf16(a[kk], b, acc[nt], 0, 0, 0);
      }
    }
  }

  #pragma unroll
  for (int nt = 0; nt < 8; nt++) {
    int col = seg * 128 + nt * 16 + l16;
    float bv = 0.f;
    if (BIAS) bv = bf2f(bias[col]);
    #pragma unroll
    for (int r = 0; r < 4; r++) {
      int row = row0 + quad * 4 + r;
      size_t oi = (size_t)row * OSTR + col;
      float v = acc[nt][r] + bv;
      if (RES) v += bf2f(res[(size_t)row * COLS + col]);
      if (RELU) v = fmaxf(v, 0.f);
      if (QSC && col < 128) v *= QSCALE;
      if (OMODE == 0)      ((ushort*)outp)[oi] = f2bf(v);
      else if (OMODE == 1) ((float*)outp)[oi] = v;
      else                 ((float*)outp)[oi] += v;
    }
  }
}

// ---------------- fused lhat / Chebyshev recurrence ----------------
__global__ __launch_bounds__(256) void spmm_cheb(
    const int* __restrict__ row_ptr, const int2* __restrict__ ep,
    const ushort* __restrict__ v,
    const ushort* __restrict__ txprev, ushort* __restrict__ txout,
    const ushort* __restrict__ lambda_max, int first, int str)
{
  int wave = threadIdx.x >> 6, lane = threadIdx.x & 63;
  int sub = lane >> 4, l16 = lane & 15;
  int d = blockIdx.x * 4 + wave;
  float lm = bf2f(lambda_max[0]);
  float scale = 2.f / lm;
  if (!(scale == scale) || fabsf(scale) > 1e6f) scale = 1.f;
  int beg = row_ptr[d];
  int end = (d == N - 1) ? E : row_ptr[d + 1];
  float acc[8] = {0.f,0.f,0.f,0.f,0.f,0.f,0.f,0.f};
  for (int jb = beg; jb < end; jb += 4) {
    int j = jb + sub;
    bool ok = j < end;
    int2 e2 = ep[ok ? j : beg];
    int s = e2.x & (N - 1);
    float w = ok ? __int_as_float(e2.y) : 0.f;
    bf16x8 vv = *(const bf16x8*)(v + (size_t)s * str + l16 * 8);
    #pragma unroll
    for (int i = 0; i < 8; i++) acc[i] += w * bf2f((ushort)vv[i]);
  }
  #pragma unroll
  for (int i = 0; i < 8; i++) {
    acc[i] += __shfl_xor(acc[i], 16);
    acc[i] += __shfl_xor(acc[i], 32);
  }
  if (sub == 0) {
    bf16x8 vd = *(const bf16x8*)(v + (size_t)d * str + l16 * 8);
    bf16x8 tp;
    if (!first) tp = *(const bf16x8*)(txprev + (size_t)d * str + l16 * 8);
    bf16x8 ov;
    #pragma unroll
    for (int i = 0; i < 8; i++) {
      float r = (scale - 1.f) * bf2f((ushort)vd[i]) - scale * acc[i];
      if (!first) r = 2.f * r - bf2f((ushort)tp[i]);
      ov[i] = (short)f2bf(r);
    }
    *(bf16x8*)(txout + (size_t)d * str + l16 * 8) = ov;
  }
}

// ---------------- U^T @ h_proj partials via MFMA ----------------
__global__ __launch_bounds__(256) void ut_mfma(const ushort* __restrict__ U,
    const ushort* __restrict__ hp, float* __restrict__ parts)
{
  constexpr int RP = 40;
  __shared__ ushort Ut[128 * RP];
  __shared__ ushort Ht[128 * RP];
  int t = threadIdx.x;
  int lane = t & 63, wave = t >> 6;
  int quad = lane >> 4, l16 = lane & 15;

  f32x4 acc[2][8];
  #pragma unroll
  for (int a = 0; a < 2; a++)
    #pragma unroll
    for (int ct = 0; ct < 8; ct++) acc[a][ct] = (f32x4){0.f, 0.f, 0.f, 0.f};

  for (int ch = 0; ch < 4; ch++) {
    int n0 = blockIdx.x * 128 + ch * 32;
    __syncthreads();
    for (int i = t; i < 2048; i += 256) {
      int r2 = i >> 7, c = i & 127;
      uint u0 = U [(size_t)(n0 + r2 * 2) * 128 + c];
      uint u1 = U [(size_t)(n0 + r2 * 2 + 1) * 128 + c];
      *(uint*)&Ut[c * RP + r2 * 2] = (u0 & 0xffffu) | (u1 << 16);
      uint h0 = hp[(size_t)(n0 + r2 * 2) * 128 + c];
      uint h1 = hp[(size_t)(n0 + r2 * 2 + 1) * 128 + c];
      *(uint*)&Ht[c * RP + r2 * 2] = (h0 & 0xffffu) | (h1 << 16);
    }
    __syncthreads();
    bf16x8 bfr[8];
    #pragma unroll
    for (int ct = 0; ct < 8; ct++)
      bfr[ct] = *(const bf16x8*)(&Ht[(ct * 16 + l16) * RP + quad * 8]);
    #pragma unroll
    for (int a = 0; a < 2; a++) {
      int kt = wave * 2 + a;
      bf16x8 af = *(const bf16x8*)(&Ut[(kt * 16 + l16) * RP + quad * 8]);
      #pragma unroll
      for (int ct = 0; ct < 8; ct++)
        acc[a][ct] = __builtin_amdgcn_mfma_f32_16x16x32_bf16(af, bfr[ct], acc[a][ct], 0, 0, 0);
    }
  }

  float* po = parts + (size_t)blockIdx.x * 16384;
  #pragma unroll
  for (int a = 0; a < 2; a++) {
    int kt = wave * 2 + a;
    #pragma unroll
    for (int ct = 0; ct < 8; ct++)
      #pragma unroll
      for (int r = 0; r < 4; r++)
        po[(kt * 16 + quad * 4 + r) * 128 + ct * 16 + l16] = acc[a][ct][r];
  }
}

__global__ __launch_bounds__(256) void reduce_mt(const float* __restrict__ parts,
    const ushort* __restrict__ Lambda, const ushort* __restrict__ gamma,
    ushort* __restrict__ MT)
{
  int e = blockIdx.x * 256 + threadIdx.x;
  int keig = e >> 7, c = e & 127;
  float s = 0.f;
  for (int p = 0; p < UT_BLOCKS; p++) s += parts[(size_t)p * 16384 + e];
  float g = bf2f(gamma[0]);
  float lam = bf2f(Lambda[keig]);
  float sl = __expf(-g * lam * lam);
  MT[c * 128 + keig] = f2bf(sl * s);
}

// ---------------- BatchNorm ----------------
__global__ __launch_bounds__(256) void bn_stats(const float* __restrict__ h,
                                                float* __restrict__ stats)
{
  int c = threadIdx.x & 127, half = threadIdx.x >> 7;
  int r0 = blockIdx.x * 128 + half;
  float s = 0.f, s2 = 0.f;
  for (int i = 0; i < 64; i++) {
    float v = sane(h[(size_t)(r0 + i * 2) * 128 + c]);
    s += v; s2 += v * v;
  }
  atomicAdd(&stats[c], s);
  atomicAdd(&stats[128 + c], s2);
}

__global__ __launch_bounds__(256) void bn_apply(const float* __restrict__ h,
    const float* __restrict__ st, const ushort* __restrict__ gw,
    const ushort* __restrict__ gb, const ushort* __restrict__ add,
    void* __restrict__ out, const uint* __restrict__ lmraw, int final_out)
{
  size_t e = ((size_t)blockIdx.x * 256 + threadIdx.x) * 4;
  int c0 = (int)(e & 127);
  float4 hv = *(const float4*)(h + e);
  float xv[4] = {sane(hv.x), sane(hv.y), sane(hv.z), sane(hv.w)};
  float addv[4] = {0.f, 0.f, 0.f, 0.f};
  if (add) {
    ushort4 av = *(const ushort4*)(add + e);
    addv[0] = bf2f(av.x); addv[1] = bf2f(av.y);
    addv[2] = bf2f(av.z); addv[3] = bf2f(av.w);
  }
  float r[4];
  #pragma unroll
  for (int j = 0; j < 4; j++) {
    int c = c0 + j;
    float mu = st[c] * (1.f / 32768.f);
    float var = fmaxf(st[128 + c] * (1.f / 32768.f) - mu * mu, 0.f);
    r[j] = (xv[j] - mu) * rsqrtf(var + EPSV) * bf2f(gw[c]) + bf2f(gb[c]) + addv[j];
  }
  if (final_out && mode_fp32(lmraw)) {
    float4 o4; o4.x = r[0]; o4.y = r[1]; o4.z = r[2]; o4.w = r[3];
    *(float4*)((float*)out + e) = o4;
  } else {
    ushort4 o;
    o.x = f2bf(r[0]); o.y = f2bf(r[1]); o.z = f2bf(r[2]); o.w = f2bf(r[3]);
    *(ushort4*)((ushort*)out + e) = o;
  }
}

// ---------------- MFMA flash attention ----------------
// 512 blocks x 512 threads (8 waves): (graph g, head hh, q-half). K and V
// staged in LDS; each wave owns 32 q-rows (2 MFMA tiles) -> 16 waves/CU for
// latency hiding. Q pre-scaled by 1/sqrt(dh)*log2e in the QKV GEMM.
__global__ __launch_bounds__(512) void attn_mfma(const ushort* __restrict__ qkv,
                                                 ushort* __restrict__ attn)
{
  constexpr int VP = 516;            // 258 words = 2 mod 32
  constexpr int KP = 40;             // 20 words -> 2-way max on b128 (free)
  __shared__ ushort Kt[512 * KP];    // 40 KB  [key][dim]
  __shared__ ushort Vt[32 * VP];     // 33 KB  [dim][key]
  int b = blockIdx.x;
  int g = b >> 3, hh = (b >> 1) & 3, half = b & 1;
  int lane = threadIdx.x & 63, wave = threadIdx.x >> 6;   // wave 0..7
  int quad = lane >> 4, l16 = lane & 15;
  const ushort* base = qkv + (size_t)g * 512 * 384;

  // stage K: one 16B fragment per (key, 8-dim chunk)
  for (int i = threadIdx.x; i < 512 * 4; i += 512) {
    int key = i >> 2, c8 = (i & 3) * 8;
    *(bf16x8*)&Kt[key * KP + c8] =
        *(const bf16x8*)(base + (size_t)key * 384 + 128 + hh * 32 + c8);
  }
  // stage V transposed, key-pairs packed as one b32 write
  for (int i = threadIdx.x; i < 256 * 8; i += 512) {
    int kp = i >> 3, d4 = (i & 7) * 4;
    const ushort* va = base + (size_t)(2 * kp) * 384 + 256 + hh * 32 + d4;
    ushort4 a = *(const ushort4*)va;
    ushort4 c = *(const ushort4*)(va + 384);
    *(uint*)&Vt[(d4 + 0) * VP + 2 * kp] = (uint)a.x | ((uint)c.x << 16);
    *(uint*)&Vt[(d4 + 1) * VP + 2 * kp] = (uint)a.y | ((uint)c.y << 16);
    *(uint*)&Vt[(d4 + 2) * VP + 2 * kp] = (uint)a.z | ((uint)c.z << 16);
    *(uint*)&Vt[(d4 + 3) * VP + 2 * kp] = (uint)a.w | ((uint)c.w << 16);
  }
  __syncthreads();

  int q0 = half * 256 + wave * 32;
  bf16x8 qf[2];
  #pragma unroll
  for (int i = 0; i < 2; i++)
    qf[i] = *(const bf16x8*)(base + (size_t)(q0 + i * 16 + l16) * 384 + hh * 32 + quad * 8);

  f32x4 O[2][2];
  #pragma unroll
  for (int dt = 0; dt < 2; dt++)
    #pragma unroll
    for (int i = 0; i < 2; i++) O[dt][i] = (f32x4){0.f, 0.f, 0.f, 0.f};
  float lsum[2] = {0.f, 0.f};

  union PU { uint u[4]; bf16x8 v; };
  union VU { uint2 a[2]; bf16x8 v; };

  for (int kt2 = 0; kt2 < 16; kt2++) {
    int k0 = kt2 * 32;
    bf16x8 kfA = *(const bf16x8*)&Kt[(k0 + l16) * KP + quad * 8];
    bf16x8 kfB = *(const bf16x8*)&Kt[(k0 + 16 + l16) * KP + quad * 8];
    PU pw[2];
    #pragma unroll
    for (int i = 0; i < 2; i++) {
      f32x4 sA = __builtin_amdgcn_mfma_f32_16x16x32_bf16(kfA, qf[i], (f32x4){0.f,0.f,0.f,0.f}, 0, 0, 0);
      f32x4 sB = __builtin_amdgcn_mfma_f32_16x16x32_bf16(kfB, qf[i], (f32x4){0.f,0.f,0.f,0.f}, 0, 0, 0);
      float p0 = fexp2(fminf(sA[0], 86.5f));
      float p1 = fexp2(fminf(sA[1], 86.5f));
      float p2 = fexp2(fminf(sA[2], 86.5f));
      float p3 = fexp2(fminf(sA[3], 86.5f));
      float p4 = fexp2(fminf(sB[0], 86.5f));
      float p5 = fexp2(fminf(sB[1], 86.5f));
      float p6 = fexp2(fminf(sB[2], 86.5f));
      float p7 = fexp2(fminf(sB[3], 86.5f));
      lsum[i] += ((p0 + p1) + (p2 + p3)) + ((p4 + p5) + (p6 + p7));
      pw[i].u[0] = cvtpk(p0, p1); pw[i].u[1] = cvtpk(p2, p3);
      pw[i].u[2] = cvtpk(p4, p5); pw[i].u[3] = cvtpk(p6, p7);
    }
    #pragma unroll
    for (int dt = 0; dt < 2; dt++) {
      int drow = (dt * 16 + l16) * VP;
      VU vu;
      vu.a[0] = *(const uint2*)&Vt[drow + k0 + quad * 4];
      vu.a[1] = *(const uint2*)&Vt[drow + k0 + 16 + quad * 4];
      #pragma unroll
      for (int i = 0; i < 2; i++)
        O[dt][i] = __builtin_amdgcn_mfma_f32_16x16x32_bf16(vu.v, pw[i].v, O[dt][i], 0, 0, 0);
    }
  }

  #pragma unroll
  for (int i = 0; i < 2; i++) {
    float l = lsum[i];
    l += __shfl_xor(l, 16);
    l += __shfl_xor(l, 32);
    lsum[i] = 1.f / l;
  }

  #pragma unroll
  for (int i = 0; i < 2; i++) {
    size_t node = (size_t)g * 512 + q0 + i * 16 + l16;
    #pragma unroll
    for (int dt = 0; dt < 2; dt++) {
      uint2 o;
      o.x = cvtpk(O[dt][i][0] * lsum[i], O[dt][i][1] * lsum[i]);
      o.y = cvtpk(O[dt][i][2] * lsum[i], O[dt][i][3] * lsum[i]);
      *(uint2*)(attn + node * 128 + hh * 32 + dt * 16 + quad * 4) = o;
    }
  }
}

// ---------------- workspace layout (bytes), total 103 MB ----------------
constexpr size_t KB = 1024;
constexpr size_t MB = 1048576;
constexpr size_t OFF_WT    = 0;                 // 576 KB
constexpr size_t OFF_CDT   = 576 * KB;          // 128 KB (cnt_dst totals)
constexpr size_t OFF_RP    = 704 * KB;          // 128 KB
constexpr size_t OFF_DIS   = 832 * KB;          // 128 KB
constexpr size_t OFF_MT    = 960 * KB;          // 32 KB
constexpr size_t OFF_STATS = 1024 * KB;         // 3 KB  [zeroed]
constexpr size_t OFF_CEI   = 6  * MB;           // 4 MB
constexpr size_t OFF_EP    = 10 * MB;           // 4 MB (packed int2 per slot)
constexpr size_t OFF_CANX  = 14 * MB;           // 8 MB; later comb
constexpr size_t OFF_CANU  = 22 * MB;           // 8 MB; later h1
constexpr size_t OFF_CANS  = 30 * MB;           // ~0.6 MB
constexpr size_t OFF_F1    = 31 * MB;           // fp32 16 MB (spec shares, dead before F1)
constexpr size_t OFF_SPEC  = 31 * MB;           // 8 MB
constexpr size_t OFF_HPROJ = 39 * MB;           // 8 MB (tmpA shares; dead before F1 write)
constexpr size_t OFF_TBIG  = 47 * MB;           // 40 MB; later qkv/mlph
constexpr size_t OFF_PARTH = OFF_TBIG;          // 8 MB hist partials (dead before Tbig)
constexpr size_t OFF_OFF2  = OFF_TBIG + 8 * MB; // 8 MB per-block slot bases
constexpr size_t OFF_PARTS = 87 * MB;           // 16 MB; attnb shares; end 103 MB

extern "C" void kernel_launch(void* const* d_in, const int* in_sizes, int n_in,
                              void* d_out, int out_size, void* d_ws, size_t ws_size,
                              hipStream_t stream) {
  (void)in_sizes; (void)n_in; (void)out_size; (void)ws_size;
  const uint* lmraw = (const uint*)d_in[3];
  const int*  ei    = (const int*)d_in[30];

  char* W = (char*)d_ws;
  ushort* wt    = (ushort*)(W + OFF_WT);
  int*    cdt   = (int*)(W + OFF_CDT);
  int*    rp    = (int*)(W + OFF_RP);
  float*  dis   = (float*)(W + OFF_DIS);
  ushort* MT    = (ushort*)(W + OFF_MT);
  float*  stats = (float*)(W + OFF_STATS);
  int*    cei   = (int*)(W + OFF_CEI);
  int2*   ep    = (int2*)(W + OFF_EP);
  ushort* part  = (ushort*)(W + OFF_PARTH);
  int*    off2  = (int*)(W + OFF_OFF2);
  ushort* canx  = (ushort*)(W + OFF_CANX);
  ushort* canu  = (ushort*)(W + OFF_CANU);
  ushort* cs    = (ushort*)(W + OFF_CANS);
  float*  F1    = (float*)(W + OFF_F1);
  ushort* spec  = (ushort*)(W + OFF_SPEC);
  ushort* tmpA  = (ushort*)(W + OFF_HPROJ);
  ushort* hproj = (ushort*)(W + OFF_HPROJ);
  ushort* Tbig  = (ushort*)(W + OFF_TBIG);
  ushort* qkvb  = (ushort*)(W + OFF_TBIG);
  ushort* mlph  = (ushort*)(W + OFF_TBIG);
  float*  parts = (float*)(W + OFF_PARTS);
  ushort* attnb = (ushort*)(W + OFF_PARTS);
  ushort* h1    = (ushort*)(W + OFF_CANU);
  ushort* comb  = (ushort*)(W + OFF_CANX);

  const ushort* cLambda = cs + COF[0];
  const ushort* cLmx    = cs + COF[1];
  const ushort* cSpa1   = cs + COF[2];
  const ushort* cBspa1  = cs + COF[3];
  const ushort* cSpa2   = cs + COF[4];
  const ushort* cBspa2  = cs + COF[5];
  const ushort* cSpe1   = cs + COF[6];
  const ushort* cBspe1  = cs + COF[7];
  const ushort* cSpe2   = cs + COF[8];
  const ushort* cBspe2  = cs + COF[9];
  const ushort* cCheb   = cs + COF[10];
  const ushort* cChebB  = cs + COF[11];
  const ushort* cGam    = cs + COF[12];
  const ushort* cProj   = cs + COF[13];
  const ushort* cQkv    = cs + COF[14];
  const ushort* cBqkv   = cs + COF[15];
  const ushort* cWout   = cs + COF[16];
  const ushort* cBout   = cs + COF[17];
  const ushort* cMw1    = cs + COF[18];
  const ushort* cMb1    = cs + COF[19];
  const ushort* cMw2    = cs + COF[20];
  const ushort* cMb2    = cs + COF[21];
  const ushort* cBn1w   = cs + COF[22];
  const ushort* cBn1b   = cs + COF[23];
  const ushort* cBn2w   = cs + COF[24];
  const ushort* cBn2b   = cs + COF[25];
  const ushort* cBn3w   = cs + COF[26];
  const ushort* cBn3b   = cs + COF[27];

  const ushort* NUL = nullptr;

  // only BN stats need zeroing (768 floats)
  zero_kernel<<<3, 256, 0, stream>>>((int*)(W + OFF_STATS), 768);

  // ---- canonicalize inputs ----
  CvtArgs ca;
  ca.src[0]  = d_in[2];  ca.src[1]  = d_in[3];  ca.src[2]  = d_in[4];
  ca.src[3]  = d_in[5];  ca.src[4]  = d_in[6];  ca.src[5]  = d_in[7];
  ca.src[6]  = d_in[8];  ca.src[7]  = d_in[9];  ca.src[8]  = d_in[10];
  ca.src[9]  = d_in[11]; ca.src[10] = d_in[12]; ca.src[11] = d_in[13];
  ca.src[12] = d_in[14]; ca.src[13] = d_in[15]; ca.src[14] = d_in[16];
  ca.src[15] = d_in[17]; ca.src[16] = d_in[18]; ca.src[17] = d_in[19];
  ca.src[18] = d_in[20]; ca.src[19] = d_in[21]; ca.src[20] = d_in[22];
  ca.src[21] = d_in[23]; ca.src[22] = d_in[24]; ca.src[23] = d_in[25];
  ca.src[24] = d_in[26]; ca.src[25] = d_in[27]; ca.src[26] = d_in[28];
  ca.src[27] = d_in[29];
  convert_small<<<(CAN_SMALL_TOTAL + 255) / 256, 256, 0, stream>>>(ca, cs, lmraw);
  convert_big<<<(2 * N * C / 4) / 256, 256, 0, stream>>>(d_in[0], d_in[1], canx, canu, lmraw);

  transpose_weights<<<1152, 256, 0, stream>>>(cSpa1, cSpa2, cSpe1, cSpe2,
      cProj, cCheb, cQkv, cWout, cMw1, cMw2, wt);

  // ---- edge prep (LDS-private histograms, no device-scope atomics) ----
  hist_lds<<<2 * HB, 1024, 0, stream>>>(ei, cei, part);
  reduce_cnt<<<N / 256, 256, 0, stream>>>(part, cdt, dis);
  scan_kernel<<<1, 1024, 0, stream>>>(cdt, rp);
  off_kernel<<<N / 256, 256, 0, stream>>>(rp, part, off2);
  edge_scatter<<<HB, 1024, 0, stream>>>(cei, off2, dis, ep);

  dim3 g1(512), g2(1024), g3(1536), bb(256);
  // ---- input MLPs (T0 = x_sp written into Tbig col-block 0) ----
  gemm_lds<128,128,true ,0,true ,false,128,128,false><<<g1, bb, 0, stream>>>(canx, wt + WT_SPA1, cBspa1, NUL, tmpA);
  gemm_lds<128,128,false,0,true ,false,128,640,false><<<g1, bb, 0, stream>>>(tmpA, wt + WT_SPA2, cBspa2, NUL, Tbig);
  gemm_lds<128,128,true ,0,true ,false,128,128,false><<<g1, bb, 0, stream>>>(canx, wt + WT_SPE1, cBspe1, NUL, tmpA);
  gemm_lds<128,128,false,0,true ,false,128,128,false><<<g1, bb, 0, stream>>>(tmpA, wt + WT_SPE2, cBspe2, NUL, spec);
  gemm_lds<128,128,false,0,false,false,128,128,false><<<g1, bb, 0, stream>>>(spec, wt + WT_PROJ, NUL,    NUL, hproj);

  // ---- spectral filter M^T ----
  ut_mfma<<<UT_BLOCKS, 256, 0, stream>>>(canu, hproj, parts);
  reduce_mt<<<64, 256, 0, stream>>>(parts, cLambda, cGam, MT);

  // ---- Chebyshev recurrence into Tbig, then one K=640 GEMM -> F1 ----
  spmm_cheb<<<N / 4, 256, 0, stream>>>(rp, ep, Tbig,       NUL,        Tbig + 128, cLmx, 1, 640);
  spmm_cheb<<<N / 4, 256, 0, stream>>>(rp, ep, Tbig + 128, Tbig,       Tbig + 256, cLmx, 0, 640);
  spmm_cheb<<<N / 4, 256, 0, stream>>>(rp, ep, Tbig + 256, Tbig + 128, Tbig + 384, cLmx, 0, 640);
  spmm_cheb<<<N / 4, 256, 0, stream>>>(rp, ep, Tbig + 384, Tbig + 256, Tbig + 512, cLmx, 0, 640);
  gemm_lds<640,128,false,1,true ,false,640,128,false><<<g1, bb, 0, stream>>>(Tbig, wt + WT_CHEB, cChebB, NUL, F1);

  // ---- out_spectral + x residual; BN1 -> h1 ----
  gemm_lds<128,128,false,2,false,true ,128,128,false><<<g1, bb, 0, stream>>>(canu, MT, NUL, canx, F1);
  bn_stats<<<256, 256, 0, stream>>>(F1, stats);
  bn_apply<<<(N * C) / 1024, 256, 0, stream>>>(F1, stats, cBn1w, cBn1b, NUL, h1, lmraw, 0);

  // ---- attention branch (Q pre-scaled in QKV epilogue) ----
  gemm_lds<128,384,false,0,true ,false,128,384,true ><<<g3, bb, 0, stream>>>(canx, wt + WT_QKV, cBqkv, NUL, qkvb);
  attn_mfma<<<512, 512, 0, stream>>>(qkvb, attnb);
  gemm_lds<128,128,false,1,true ,true ,128,128,false><<<g1, bb, 0, stream>>>(attnb, wt + WT_WOUT, cBout, canx, F1);
  bn_stats<<<256, 256, 0, stream>>>(F1, stats + 256);
  bn_apply<<<(N * C) / 1024, 256, 0, stream>>>(F1, stats + 256, cBn2w, cBn2b, h1, comb, lmraw, 0);

  // ---- MLP + final BN ----
  gemm_lds<128,256,true ,0,true ,false,128,256,false><<<g2, bb, 0, stream>>>(comb, wt + WT_MLP1, cMb1, NUL, mlph);
  gemm_lds<256,128,false,1,true ,true ,256,128,false><<<g1, bb, 0, stream>>>(mlph, wt + WT_MLP2, cMb2, comb, F1);
  bn_stats<<<256, 256, 0, stream>>>(F1, stats + 512);
  bn_apply<<<(N * C) / 1024, 256, 0, stream>>>(F1, stats + 512, cBn3w, cBn3b, NUL, d_out, lmraw, 1);
}

// Round 4
// 538.254 us; speedup vs baseline: 1.0730x; 1.0049x over previous
//
#include <hip/hip_runtime.h>

typedef short bf16x8 __attribute__((ext_vector_type(8)));
typedef short bf16x4 __attribute__((ext_vector_type(4)));
typedef float f32x4 __attribute__((ext_vector_type(4)));

#define DEVI __device__ __forceinline__

constexpr int N   = 32768;
constexpr int C   = 128;
constexpr int E   = 524288;
constexpr float EPSV = 1e-5f;
constexpr int UT_BLOCKS = 128;   // each block covers 256 rows (8 chunks of 32)
constexpr int HB  = 64;          // histogram blocks per edge-array (src / dst)
constexpr int EPB = E / HB;      // 8192 edges per histogram block
// softmax scale folded into Q at QKV-GEMM epilogue: 1/sqrt(32) * log2(e)
constexpr float QSCALE = 0.17677669529663687f * 1.4426950408889634f;

DEVI float bf2f(ushort u){ return __uint_as_float(((uint)u) << 16); }
DEVI ushort f2bf(float f){
  uint u = __float_as_uint(f);
  return (ushort)((u + 0x7fffu + ((u >> 16) & 1u)) >> 16);
}
// packed f32 pair -> bf16 pair (round-to-nearest-even), single HW instr
DEVI uint cvtpk(float lo, float hi){
  uint r;
  asm("v_cvt_pk_bf16_f32 %0, %1, %2" : "=v"(r) : "v"(lo), "v"(hi));
  return r;
}
// single-instruction 2^x (no libm edge-case code)
DEVI float fexp2(float x){
  float r;
  asm("v_exp_f32 %0, %1" : "=v"(r) : "v"(x));
  return r;
}
DEVI float sane(float v){ if (!(v == v)) return 0.f; return fminf(fmaxf(v, -1e30f), 1e30f); }
DEVI bool mode_fp32(const uint* lmraw){ return (lmraw[0] & 0xffffu) == 0u; }

// ---------------- canonical small-input table ----------------
constexpr int CSZ[28] = {128,1,16384,128,16384,128,16384,128,16384,128,81920,128,
                         1,16384,49152,384,16384,128,32768,256,32768,128,
                         128,128,128,128,128,128};
constexpr int COF[28] = {0,128,192,16576,16704,33088,33216,49600,49728,66112,
                         66240,148160,148288,148352,164736,213888,214272,230656,
                         230784,263552,263808,296576,296704,296832,296960,297088,
                         297216,297344};
constexpr int CAN_SMALL_TOTAL = 297472;

struct CvtArgs { const void* src[28]; };

__global__ __launch_bounds__(256) void convert_small(CvtArgs a, ushort* __restrict__ can,
                                                     const uint* __restrict__ lmraw)
{
  bool f32 = mode_fp32(lmraw);
  int idx = blockIdx.x * 256 + threadIdx.x;
  #pragma unroll 1
  for (int s = 0; s < 28; s++) {
    if (idx < CSZ[s]) {
      ushort v = f32 ? f2bf(((const float*)a.src[s])[idx])
                     : ((const ushort*)a.src[s])[idx];
      can[COF[s] + idx] = v;
      return;
    }
    idx -= CSZ[s];
  }
}

__global__ __launch_bounds__(256) void convert_big(const void* __restrict__ xs,
    const void* __restrict__ Us, ushort* __restrict__ canx, ushort* __restrict__ canu,
    const uint* __restrict__ lmraw)
{
  bool f32 = mode_fp32(lmraw);
  size_t e = ((size_t)blockIdx.x * 256 + threadIdx.x) * 4;
  bool isU = e >= (size_t)N * C;
  size_t off = isU ? e - (size_t)N * C : e;
  const void* src = isU ? Us : xs;
  ushort* dst = isU ? canu : canx;
  ushort4 o;
  if (f32) {
    float4 v = *(const float4*)((const float*)src + off);
    o.x = f2bf(v.x); o.y = f2bf(v.y); o.z = f2bf(v.z); o.w = f2bf(v.w);
  } else {
    o = *(const ushort4*)((const ushort*)src + off);
  }
  *(ushort4*)(dst + off) = o;
}

// ---------------- edge prep: LDS-private histograms (no device atomics) ----
__global__ __launch_bounds__(1024) void hist_lds(const int* __restrict__ ei,
    int* __restrict__ cei, ushort* __restrict__ part)
{
  __shared__ uint hist[N / 2];          // 64 KB, two bins per word
  int t = threadIdx.x;
  int b = blockIdx.x;
  bool i64 = ((ei[1] | ei[3] | ei[5] | ei[7]) == 0);
  size_t j0 = (size_t)b * EPB;
  #pragma unroll
  for (int i = t; i < N / 2; i += 1024) hist[i] = 0u;
  __syncthreads();
  for (int k = t; k < EPB; k += 1024) {
    size_t j = j0 + k;
    int v = (i64 ? ei[2 * j] : ei[j]) & (N - 1);
    cei[j] = v;
    atomicAdd(&hist[v >> 1], 1u << ((v & 1) * 16));
  }
  __syncthreads();
  uint* po = (uint*)(part + (size_t)b * N);
  for (int i = t; i < N / 2; i += 1024) po[i] = hist[i];
}

// fold partials: src totals -> dis, dst totals -> cdt
__global__ __launch_bounds__(256) void reduce_cnt(const ushort* __restrict__ part,
    int* __restrict__ cdt, float* __restrict__ dis)
{
  int d = blockIdx.x * 256 + threadIdx.x;
  int s = 0, tt = 0;
  #pragma unroll 8
  for (int b = 0; b < HB; b++) s  += part[(size_t)b * N + d];
  #pragma unroll 8
  for (int b = 0; b < HB; b++) tt += part[(size_t)(HB + b) * N + d];
  cdt[d] = tt;
  dis[d] = s > 0 ? rsqrtf((float)s) : 0.f;
}

__global__ __launch_bounds__(1024) void scan_kernel(const int* __restrict__ cnt,
                                                    int* __restrict__ row_ptr)
{
  __shared__ int sums[1024];
  int t = threadIdx.x;
  int loc[32]; int s = 0;
  int base = t * 32;
  #pragma unroll
  for (int i = 0; i < 32; i++) { loc[i] = s; s += cnt[base + i]; }
  sums[t] = s;
  __syncthreads();
  for (int off = 1; off < 1024; off <<= 1) {
    int v = (t >= off) ? sums[t - off] : 0;
    __syncthreads();
    sums[t] += v;
    __syncthreads();
  }
  int pre = (t == 0) ? 0 : sums[t - 1];
  #pragma unroll
  for (int i = 0; i < 32; i++) row_ptr[base + i] = pre + loc[i];
}

// per-hist-block slot bases: off2[b][d] = rp[d] + sum_{b'<b} partD[b'][d]
__global__ __launch_bounds__(256) void off_kernel(const int* __restrict__ rp,
    const ushort* __restrict__ part, int* __restrict__ off2)
{
  int d = blockIdx.x * 256 + threadIdx.x;
  int run = rp[d];
  #pragma unroll 8
  for (int b = 0; b < HB; b++) {
    off2[(size_t)b * N + d] = run;
    run += part[(size_t)(HB + b) * N + d];
  }
}

// deterministic scatter: block b replays its edge slice, ranks via LDS atomics
__global__ __launch_bounds__(1024) void edge_scatter(const int* __restrict__ cei,
    const int* __restrict__ off2, const float* __restrict__ dis,
    int2* __restrict__ ep)
{
  __shared__ int base[N];               // 128 KB slot cursors
  int t = threadIdx.x;
  int b = blockIdx.x;                   // 0..HB-1
  for (int i = t; i < N; i += 1024) base[i] = off2[(size_t)b * N + i];
  __syncthreads();
  size_t e0 = (size_t)b * EPB;
  for (int k = t; k < EPB; k += 1024) {
    size_t e = e0 + k;
    int s = cei[e], d = cei[e + E];
    int slot = atomicAdd(&base[d], 1);
    int2 v; v.x = s; v.y = __float_as_int(dis[s] * dis[d]);
    ep[slot] = v;
  }
}

// ---------------- weight pre-transpose ----------------
constexpr int WT_SPA1 = 0;
constexpr int WT_SPA2 = 16384;
constexpr int WT_SPE1 = 32768;
constexpr int WT_SPE2 = 49152;
constexpr int WT_PROJ = 65536;
constexpr int WT_CHEB = 81920;    // 128 x 640 (concat layout)
constexpr int WT_QKV  = 163840;   // 384 x 128
constexpr int WT_WOUT = 212992;
constexpr int WT_MLP1 = 229376;   // 256 x 128
constexpr int WT_MLP2 = 262144;   // 128 x 256
constexpr int WT_TOTAL = 294912;

__global__ __launch_bounds__(256) void zero_kernel(int* __restrict__ p, int n)
{
  int i = blockIdx.x * 256 + threadIdx.x;
  if (i < n) p[i] = 0;
}

__global__ __launch_bounds__(256) void transpose_weights(
    const ushort* __restrict__ spa1, const ushort* __restrict__ spa2,
    const ushort* __restrict__ spe1, const ushort* __restrict__ spe2,
    const ushort* __restrict__ proj, const ushort* __restrict__ cheb,
    const ushort* __restrict__ qkv,  const ushort* __restrict__ wout,
    const ushort* __restrict__ mlp1, const ushort* __restrict__ mlp2,
    ushort* __restrict__ wt)
{
  int i = blockIdx.x * 256 + threadIdx.x;
  if (i < 81920) {
    int m = i >> 14, r = i & 16383; int k = r >> 7, n = r & 127;
    const ushort* src = m==0?spa1 : m==1?spa2 : m==2?spe1 : m==3?spe2 : proj;
    wt[m*16384 + n*128 + k] = src[r];
  } else if (i < 163840) {
    int j = i - 81920; int m = j >> 14, r = j & 16383; int k = r >> 7, n = r & 127;
    wt[WT_CHEB + n*640 + m*128 + k] = cheb[j];
  } else if (i < 212992) {
    int j = i - 163840; int k = j / 384, n = j % 384;
    wt[WT_QKV + n*128 + k] = qkv[j];
  } else if (i < 229376) {
    int j = i - 212992; int k = j >> 7, n = j & 127;
    wt[WT_WOUT + n*128 + k] = wout[j];
  } else if (i < 262144) {
    int j = i - 229376; int k = j >> 8, n = j & 255;
    wt[WT_MLP1 + n*128 + k] = mlp1[j];
  } else if (i < WT_TOTAL) {
    int j = i - 262144; int k = j >> 7, n = j & 127;
    wt[WT_MLP2 + n*256 + k] = mlp2[j];
  }
}

// ---------------- LDS-staged MFMA GEMM ----------------
template<int K, int COLS, bool RELU, int OMODE, bool BIAS, bool RES, int ASTR, int OSTR, bool QSC>
__global__ __launch_bounds__(256) void gemm_lds(
    const ushort* __restrict__ A, const ushort* __restrict__ WT,
    const ushort* __restrict__ bias, const ushort* __restrict__ res,
    void* __restrict__ outp)
{
  constexpr int NSEG = COLS / 128;
  constexpr int NKC = K / 128;
  constexpr int BP = 136;
  __shared__ ushort Bs[128 * BP];
  int tid = threadIdx.x;
  int lane = tid & 63, wave = tid >> 6;
  int quad = lane >> 4, l16 = lane & 15;
  int seg = (NSEG > 1) ? (blockIdx.x % NSEG) : 0;
  int rb  = (NSEG > 1) ? (blockIdx.x / NSEG) : blockIdx.x;
  int row0 = rb * 64 + wave * 16;
  const ushort* wseg = WT + (size_t)(seg * 128) * K;

  f32x4 acc[8];
  #pragma unroll
  for (int nt = 0; nt < 8; nt++) acc[nt] = (f32x4){0.f, 0.f, 0.f, 0.f};

  for (int kc = 0; kc < NKC; kc++) {
    if (kc) __syncthreads();
    #pragma unroll
    for (int i = tid; i < 2048; i += 256) {
      int col = i >> 4, ko = (i & 15) * 8;
      *(bf16x8*)&Bs[col * BP + ko] =
          *(const bf16x8*)(wseg + (size_t)col * K + kc * 128 + ko);
    }
    __syncthreads();
    bf16x8 a[4];
    const ushort* ap = A + (size_t)(row0 + l16) * ASTR + kc * 128 + quad * 8;
    #pragma unroll
    for (int kk = 0; kk < 4; kk++) a[kk] = *(const bf16x8*)(ap + kk * 32);
    #pragma unroll
    for (int kk = 0; kk < 4; kk++) {
      #pragma unroll
      for (int nt = 0; nt < 8; nt++) {
        bf16x8 b = *(const bf16x8*)(&Bs[(nt * 16 + l16) * BP + kk * 32 + quad * 8]);
        acc[nt] = __builtin_amdgcn_mfma_f32_16x16x32_bf16(a[kk], b, acc[nt], 0, 0, 0);
      }
    }
  }

  #pragma unroll
  for (int nt = 0; nt < 8; nt++) {
    int col = seg * 128 + nt * 16 + l16;
    float bv = 0.f;
    if (BIAS) bv = bf2f(bias[col]);
    #pragma unroll
    for (int r = 0; r < 4; r++) {
      int row = row0 + quad * 4 + r;
      size_t oi = (size_t)row * OSTR + col;
      float v = acc[nt][r] + bv;
      if (RES) v += bf2f(res[(size_t)row * COLS + col]);
      if (RELU) v = fmaxf(v, 0.f);
      if (QSC && col < 128) v *= QSCALE;
      if (OMODE == 0)      ((ushort*)outp)[oi] = f2bf(v);
      else if (OMODE == 1) ((float*)outp)[oi] = v;
      else                 ((float*)outp)[oi] += v;
    }
  }
}

// ---------------- fused 2/3-stage 128->128 GEMM chain ----------------
// OUT = [stage3?] ((relu(A@W1+B1))@W2+B2) [@W3]   all dims 128, bf16
// Intermediates kept in LDS as bf16 (identical rounding to the unfused path).
template<bool THIRD, int OSTR>
__global__ __launch_bounds__(256) void gemm_chain(
    const ushort* __restrict__ A,
    const ushort* __restrict__ W1, const ushort* __restrict__ B1,
    const ushort* __restrict__ W2, const ushort* __restrict__ B2,
    const ushort* __restrict__ W3,
    ushort* __restrict__ outp)
{
  constexpr int BP = 136;
  __shared__ ushort Bs[128 * BP];   // weight staging (34 KB)
  __shared__ ushort Ts[64 * BP];    // 64-row intermediate (17 KB)
  int tid = threadIdx.x;
  int lane = tid & 63, wave = tid >> 6;
  int quad = lane >> 4, l16 = lane & 15;
  int row0 = blockIdx.x * 64 + wave * 16;
  int lw = wave * 16;               // local row base for this wave

  // ---- stage 1: A(global) @ W1, relu ----
  for (int i = tid; i < 2048; i += 256) {
    int col = i >> 4, ko = (i & 15) * 8;
    *(bf16x8*)&Bs[col * BP + ko] = *(const bf16x8*)(W1 + (size_t)col * 128 + ko);
  }
  __syncthreads();
  bf16x8 a[4];
  {
    const ushort* ap = A + (size_t)(row0 + l16) * 128 + quad * 8;
    #pragma unroll
    for (int kk = 0; kk < 4; kk++) a[kk] = *(const bf16x8*)(ap + kk * 32);
  }
  f32x4 acc[8];
  #pragma unroll
  for (int nt = 0; nt < 8; nt++) acc[nt] = (f32x4){0.f, 0.f, 0.f, 0.f};
  #pragma unroll
  for (int kk = 0; kk < 4; kk++)
    #pragma unroll
    for (int nt = 0; nt < 8; nt++) {
      bf16x8 b = *(const bf16x8*)(&Bs[(nt * 16 + l16) * BP + kk * 32 + quad * 8]);
      acc[nt] = __builtin_amdgcn_mfma_f32_16x16x32_bf16(a[kk], b, acc[nt], 0, 0, 0);
    }
  #pragma unroll
  for (int nt = 0; nt < 8; nt++) {
    int col = nt * 16 + l16;
    float bv = bf2f(B1[col]);
    #pragma unroll
    for (int r = 0; r < 4; r++)
      Ts[(lw + quad * 4 + r) * BP + col] = f2bf(fmaxf(acc[nt][r] + bv, 0.f));
  }
  __syncthreads();

  // ---- stage 2: Ts @ W2 + B2 ----
  for (int i = tid; i < 2048; i += 256) {
    int col = i >> 4, ko = (i & 15) * 8;
    *(bf16x8*)&Bs[col * BP + ko] = *(const bf16x8*)(W2 + (size_t)col * 128 + ko);
  }
  #pragma unroll
  for (int kk = 0; kk < 4; kk++)
    a[kk] = *(const bf16x8*)(&Ts[(lw + l16) * BP + kk * 32 + quad * 8]);
  __syncthreads();
  #pragma unroll
  for (int nt = 0; nt < 8; nt++) acc[nt] = (f32x4){0.f, 0.f, 0.f, 0.f};
  #pragma unroll
  for (int kk = 0; kk < 4; kk++)
    #pragma unroll
    for (int nt = 0; nt < 8; nt++) {
      bf16x8 b = *(const bf16x8*)(&Bs[(nt * 16 + l16) * BP + kk * 32 + quad * 8]);
      acc[nt] = __builtin_amdgcn_mfma_f32_16x16x32_bf16(a[kk], b, acc[nt], 0, 0, 0);
    }

  if (!THIRD) {
    #pragma unroll
    for (int nt = 0; nt < 8; nt++) {
      int col = nt * 16 + l16;
      float bv = bf2f(B2[col]);
      #pragma unroll
      for (int r = 0; r < 4; r++)
        outp[(size_t)(row0 + quad * 4 + r) * OSTR + col] = f2bf(acc[nt][r] + bv);
    }
    return;
  }

  // ---- stage 3 (spe chain): (stage2) @ W3, no bias ----
  __syncthreads();                    // all stage-2 Bs reads & Ts reads done
  #pragma unroll
  for (int nt = 0; nt < 8; nt++) {
    int col = nt * 16 + l16;
    float bv = bf2f(B2[col]);
    #pragma unroll
    for (int r = 0; r < 4; r++)
      Ts[(lw + quad * 4 + r) * BP + col] = f2bf(acc[nt][r] + bv);
  }
  __syncthreads();
  for (int i = tid; i < 2048; i += 256) {
    int col = i >> 4, ko = (i & 15) * 8;
    *(bf16x8*)&Bs[col * BP + ko] = *(const bf16x8*)(W3 + (size_t)col * 128 + ko);
  }
  #pragma unroll
  for (int kk = 0; kk < 4; kk++)
    a[kk] = *(const bf16x8*)(&Ts[(lw + l16) * BP + kk * 32 + quad * 8]);
  __syncthreads();
  #pragma unroll
  for (int nt = 0; nt < 8; nt++) acc[nt] = (f32x4){0.f, 0.f, 0.f, 0.f};
  #pragma unroll
  for (int kk = 0; kk < 4; kk++)
    #pragma unroll
    for (int nt = 0; nt < 8; nt++) {
      bf16x8 b = *(const bf16x8*)(&Bs[(nt * 16 + l16) * BP + kk * 32 + quad * 8]);
      acc[nt] = __builtin_amdgcn_mfma_f32_16x16x32_bf16(a[kk], b, acc[nt], 0, 0, 0);
    }
  #pragma unroll
  for (int nt = 0; nt < 8; nt++) {
    int col = nt * 16 + l16;
    #pragma unroll
    for (int r = 0; r < 4; r++)
      outp[(size_t)(row0 + quad * 4 + r) * OSTR + col] = f2bf(acc[nt][r]);
  }
}

// ---------------- fused MLP: F1 = (relu(A@W1+B1))@W2 + B2 + res ----------------
// W1: 128->256, W2: 256->128. Hidden kept in LDS as bf16 (same rounding).
__global__ __launch_bounds__(256) void gemm_mlp(
    const ushort* __restrict__ A,
    const ushort* __restrict__ W1, const ushort* __restrict__ B1,
    const ushort* __restrict__ W2, const ushort* __restrict__ B2,
    const ushort* __restrict__ res, float* __restrict__ outp)
{
  constexpr int BP = 136;
  constexpr int HP = 264;
  __shared__ ushort Bs[128 * BP];   // 34 KB weight staging
  __shared__ ushort Hs[64 * HP];    // 33 KB hidden (64 x 256, pad 8)
  int tid = threadIdx.x;
  int lane = tid & 63, wave = tid >> 6;
  int quad = lane >> 4, l16 = lane & 15;
  int row0 = blockIdx.x * 64 + wave * 16;
  int lw = wave * 16;

  bf16x8 a[4];
  {
    const ushort* ap = A + (size_t)(row0 + l16) * 128 + quad * 8;
    #pragma unroll
    for (int kk = 0; kk < 4; kk++) a[kk] = *(const bf16x8*)(ap + kk * 32);
  }

  // ---- stage 1: two 128-col segments of the 256-wide hidden ----
  for (int seg = 0; seg < 2; seg++) {
    if (seg) __syncthreads();
    for (int i = tid; i < 2048; i += 256) {
      int col = i >> 4, ko = (i & 15) * 8;
      *(bf16x8*)&Bs[col * BP + ko] =
          *(const bf16x8*)(W1 + (size_t)(seg * 128 + col) * 128 + ko);
    }
    __syncthreads();
    f32x4 acc[8];
    #pragma unroll
    for (int nt = 0; nt < 8; nt++) acc[nt] = (f32x4){0.f, 0.f, 0.f, 0.f};
    #pragma unroll
    for (int kk = 0; kk < 4; kk++)
      #pragma unroll
      for (int nt = 0; nt < 8; nt++) {
        bf16x8 b = *(const bf16x8*)(&Bs[(nt * 16 + l16) * BP + kk * 32 + quad * 8]);
        acc[nt] = __builtin_amdgcn_mfma_f32_16x16x32_bf16(a[kk], b, acc[nt], 0, 0, 0);
      }
    #pragma unroll
    for (int nt = 0; nt < 8; nt++) {
      int col = seg * 128 + nt * 16 + l16;
      float bv = bf2f(B1[col]);
      #pragma unroll
      for (int r = 0; r < 4; r++)
        Hs[(lw + quad * 4 + r) * HP + col] = f2bf(fmaxf(acc[nt][r] + bv, 0.f));
    }
  }
  __syncthreads();

  // ---- stage 2: K=256 over the LDS hidden ----
  f32x4 acc2[8];
  #pragma unroll
  for (int nt = 0; nt < 8; nt++) acc2[nt] = (f32x4){0.f, 0.f, 0.f, 0.f};
  for (int kc = 0; kc < 2; kc++) {
    if (kc) __syncthreads();
    for (int i = tid; i < 2048; i += 256) {
      int col = i >> 4, ko = (i & 15) * 8;
      *(bf16x8*)&Bs[col * BP + ko] =
          *(const bf16x8*)(W2 + (size_t)col * 256 + kc * 128 + ko);
    }
    bf16x8 a2[4];
    #pragma unroll
    for (int kk = 0; kk < 4; kk++)
      a2[kk] = *(const bf16x8*)(&Hs[(lw + l16) * HP + kc * 128 + kk * 32 + quad * 8]);
    __syncthreads();
    #pragma unroll
    for (int kk = 0; kk < 4; kk++)
      #pragma unroll
      for (int nt = 0; nt < 8; nt++) {
        bf16x8 b = *(const bf16x8*)(&Bs[(nt * 16 + l16) * BP + kk * 32 + quad * 8]);
        acc2[nt] = __builtin_amdgcn_mfma_f32_16x16x32_bf16(a2[kk], b, acc2[nt], 0, 0, 0);
      }
  }

  #pragma unroll
  for (int nt = 0; nt < 8; nt++) {
    int col = nt * 16 + l16;
    float bv = bf2f(B2[col]);
    #pragma unroll
    for (int r = 0; r < 4; r++) {
      int row = row0 + quad * 4 + r;
      float v = acc2[nt][r] + bv + bf2f(res[(size_t)row * 128 + col]);
      outp[(size_t)row * 128 + col] = v;
    }
  }
}

// ---------------- fused lhat / Chebyshev recurrence ----------------
__global__ __launch_bounds__(256) void spmm_cheb(
    const int* __restrict__ row_ptr, const int2* __restrict__ ep,
    const ushort* __restrict__ v,
    const ushort* __restrict__ txprev, ushort* __restrict__ txout,
    const ushort* __restrict__ lambda_max, int first, int str)
{
  int wave = threadIdx.x >> 6, lane = threadIdx.x & 63;
  int sub = lane >> 4, l16 = lane & 15;
  int d = blockIdx.x * 4 + wave;
  float lm = bf2f(lambda_max[0]);
  float scale = 2.f / lm;
  if (!(scale == scale) || fabsf(scale) > 1e6f) scale = 1.f;
  int beg = row_ptr[d];
  int end = (d == N - 1) ? E : row_ptr[d + 1];
  float acc[8] = {0.f,0.f,0.f,0.f,0.f,0.f,0.f,0.f};
  for (int jb = beg; jb < end; jb += 4) {
    int j = jb + sub;
    bool ok = j < end;
    int2 e2 = ep[ok ? j : beg];
    int s = e2.x & (N - 1);
    float w = ok ? __int_as_float(e2.y) : 0.f;
    bf16x8 vv = *(const bf16x8*)(v + (size_t)s * str + l16 * 8);
    #pragma unroll
    for (int i = 0; i < 8; i++) acc[i] += w * bf2f((ushort)vv[i]);
  }
  #pragma unroll
  for (int i = 0; i < 8; i++) {
    acc[i] += __shfl_xor(acc[i], 16);
    acc[i] += __shfl_xor(acc[i], 32);
  }
  if (sub == 0) {
    bf16x8 vd = *(const bf16x8*)(v + (size_t)d * str + l16 * 8);
    bf16x8 tp;
    if (!first) tp = *(const bf16x8*)(txprev + (size_t)d * str + l16 * 8);
    bf16x8 ov;
    #pragma unroll
    for (int i = 0; i < 8; i++) {
      float r = (scale - 1.f) * bf2f((ushort)vd[i]) - scale * acc[i];
      if (!first) r = 2.f * r - bf2f((ushort)tp[i]);
      ov[i] = (short)f2bf(r);
    }
    *(bf16x8*)(txout + (size_t)d * str + l16 * 8) = ov;
  }
}

// ---------------- U^T @ h_proj partials via MFMA ----------------
__global__ __launch_bounds__(256) void ut_mfma(const ushort* __restrict__ U,
    const ushort* __restrict__ hp, float* __restrict__ parts)
{
  constexpr int RP = 40;
  __shared__ ushort Ut[128 * RP];
  __shared__ ushort Ht[128 * RP];
  int t = threadIdx.x;
  int lane = t & 63, wave = t >> 6;
  int quad = lane >> 4, l16 = lane & 15;

  f32x4 acc[2][8];
  #pragma unroll
  for (int a = 0; a < 2; a++)
    #pragma unroll
    for (int ct = 0; ct < 8; ct++) acc[a][ct] = (f32x4){0.f, 0.f, 0.f, 0.f};

  for (int ch = 0; ch < 8; ch++) {
    int n0 = blockIdx.x * 256 + ch * 32;
    __syncthreads();
    for (int i = t; i < 2048; i += 256) {
      int r2 = i >> 7, c = i & 127;
      uint u0 = U [(size_t)(n0 + r2 * 2) * 128 + c];
      uint u1 = U [(size_t)(n0 + r2 * 2 + 1) * 128 + c];
      *(uint*)&Ut[c * RP + r2 * 2] = (u0 & 0xffffu) | (u1 << 16);
      uint h0 = hp[(size_t)(n0 + r2 * 2) * 128 + c];
      uint h1 = hp[(size_t)(n0 + r2 * 2 + 1) * 128 + c];
      *(uint*)&Ht[c * RP + r2 * 2] = (h0 & 0xffffu) | (h1 << 16);
    }
    __syncthreads();
    bf16x8 bfr[8];
    #pragma unroll
    for (int ct = 0; ct < 8; ct++)
      bfr[ct] = *(const bf16x8*)(&Ht[(ct * 16 + l16) * RP + quad * 8]);
    #pragma unroll
    for (int a = 0; a < 2; a++) {
      int kt = wave * 2 + a;
      bf16x8 af = *(const bf16x8*)(&Ut[(kt * 16 + l16) * RP + quad * 8]);
      #pragma unroll
      for (int ct = 0; ct < 8; ct++)
        acc[a][ct] = __builtin_amdgcn_mfma_f32_16x16x32_bf16(af, bfr[ct], acc[a][ct], 0, 0, 0);
    }
  }

  float* po = parts + (size_t)blockIdx.x * 16384;
  #pragma unroll
  for (int a = 0; a < 2; a++) {
    int kt = wave * 2 + a;
    #pragma unroll
    for (int ct = 0; ct < 8; ct++)
      #pragma unroll
      for (int r = 0; r < 4; r++)
        po[(kt * 16 + quad * 4 + r) * 128 + ct * 16 + l16] = acc[a][ct][r];
  }
}

__global__ __launch_bounds__(256) void reduce_mt(const float* __restrict__ parts,
    const ushort* __restrict__ Lambda, const ushort* __restrict__ gamma,
    ushort* __restrict__ MT)
{
  int e = blockIdx.x * 256 + threadIdx.x;
  int keig = e >> 7, c = e & 127;
  float s = 0.f;
  for (int p = 0; p < UT_BLOCKS; p++) s += parts[(size_t)p * 16384 + e];
  float g = bf2f(gamma[0]);
  float lam = bf2f(Lambda[keig]);
  float sl = __expf(-g * lam * lam);
  MT[c * 128 + keig] = f2bf(sl * s);
}

// ---------------- BatchNorm ----------------
__global__ __launch_bounds__(256) void bn_stats(const float* __restrict__ h,
                                                float* __restrict__ stats)
{
  int c = threadIdx.x & 127, half = threadIdx.x >> 7;
  int r0 = blockIdx.x * 128 + half;
  float s = 0.f, s2 = 0.f;
  for (int i = 0; i < 64; i++) {
    float v = sane(h[(size_t)(r0 + i * 2) * 128 + c]);
    s += v; s2 += v * v;
  }
  atomicAdd(&stats[c], s);
  atomicAdd(&stats[128 + c], s2);
}

__global__ __launch_bounds__(256) void bn_apply(const float* __restrict__ h,
    const float* __restrict__ st, const ushort* __restrict__ gw,
    const ushort* __restrict__ gb, const ushort* __restrict__ add,
    void* __restrict__ out, const uint* __restrict__ lmraw, int final_out)
{
  size_t e = ((size_t)blockIdx.x * 256 + threadIdx.x) * 4;
  int c0 = (int)(e & 127);
  float4 hv = *(const float4*)(h + e);
  float xv[4] = {sane(hv.x), sane(hv.y), sane(hv.z), sane(hv.w)};
  float addv[4] = {0.f, 0.f, 0.f, 0.f};
  if (add) {
    ushort4 av = *(const ushort4*)(add + e);
    addv[0] = bf2f(av.x); addv[1] = bf2f(av.y);
    addv[2] = bf2f(av.z); addv[3] = bf2f(av.w);
  }
  float r[4];
  #pragma unroll
  for (int j = 0; j < 4; j++) {
    int c = c0 + j;
    float mu = st[c] * (1.f / 32768.f);
    float var = fmaxf(st[128 + c] * (1.f / 32768.f) - mu * mu, 0.f);
    r[j] = (xv[j] - mu) * rsqrtf(var + EPSV) * bf2f(gw[c]) + bf2f(gb[c]) + addv[j];
  }
  if (final_out && mode_fp32(lmraw)) {
    float4 o4; o4.x = r[0]; o4.y = r[1]; o4.z = r[2]; o4.w = r[3];
    *(float4*)((float*)out + e) = o4;
  } else {
    ushort4 o;
    o.x = f2bf(r[0]); o.y = f2bf(r[1]); o.z = f2bf(r[2]); o.w = f2bf(r[3]);
    *(ushort4*)((ushort*)out + e) = o;
  }
}

// ---------------- MFMA flash attention ----------------
// 512 blocks x 512 threads (8 waves): (graph g, head hh, q-half). K and V
// staged in LDS; each wave owns 32 q-rows (2 MFMA tiles) -> 16 waves/CU for
// latency hiding. Q pre-scaled by 1/sqrt(dh)*log2e in the QKV GEMM.
__global__ __launch_bounds__(512) void attn_mfma(const ushort* __restrict__ qkv,
                                                 ushort* __restrict__ attn)
{
  constexpr int VP = 516;            // 258 words = 2 mod 32
  constexpr int KP = 40;             // 20 words -> 2-way max on b128 (free)
  __shared__ ushort Kt[512 * KP];    // 40 KB  [key][dim]
  __shared__ ushort Vt[32 * VP];     // 33 KB  [dim][key]
  int b = blockIdx.x;
  int g = b >> 3, hh = (b >> 1) & 3, half = b & 1;
  int lane = threadIdx.x & 63, wave = threadIdx.x >> 6;   // wave 0..7
  int quad = lane >> 4, l16 = lane & 15;
  const ushort* base = qkv + (size_t)g * 512 * 384;

  // stage K: one 16B fragment per (key, 8-dim chunk)
  for (int i = threadIdx.x; i < 512 * 4; i += 512) {
    int key = i >> 2, c8 = (i & 3) * 8;
    *(bf16x8*)&Kt[key * KP + c8] =
        *(const bf16x8*)(base + (size_t)key * 384 + 128 + hh * 32 + c8);
  }
  // stage V transposed, key-pairs packed as one b32 write
  for (int i = threadIdx.x; i < 256 * 8; i += 512) {
    int kp = i >> 3, d4 = (i & 7) * 4;
    const ushort* va = base + (size_t)(2 * kp) * 384 + 256 + hh * 32 + d4;
    ushort4 a = *(const ushort4*)va;
    ushort4 c = *(const ushort4*)(va + 384);
    *(uint*)&Vt[(d4 + 0) * VP + 2 * kp] = (uint)a.x | ((uint)c.x << 16);
    *(uint*)&Vt[(d4 + 1) * VP + 2 * kp] = (uint)a.y | ((uint)c.y << 16);
    *(uint*)&Vt[(d4 + 2) * VP + 2 * kp] = (uint)a.z | ((uint)c.z << 16);
    *(uint*)&Vt[(d4 + 3) * VP + 2 * kp] = (uint)a.w | ((uint)c.w << 16);
  }
  __syncthreads();

  int q0 = half * 256 + wave * 32;
  bf16x8 qf[2];
  #pragma unroll
  for (int i = 0; i < 2; i++)
    qf[i] = *(const bf16x8*)(base + (size_t)(q0 + i * 16 + l16) * 384 + hh * 32 + quad * 8);

  f32x4 O[2][2];
  #pragma unroll
  for (int dt = 0; dt < 2; dt++)
    #pragma unroll
    for (int i = 0; i < 2; i++) O[dt][i] = (f32x4){0.f, 0.f, 0.f, 0.f};
  float lsum[2] = {0.f, 0.f};

  union PU { uint u[4]; bf16x8 v; };
  union VU { uint2 a[2]; bf16x8 v; };

  for (int kt2 = 0; kt2 < 16; kt2++) {
    int k0 = kt2 * 32;
    bf16x8 kfA = *(const bf16x8*)&Kt[(k0 + l16) * KP + quad * 8];
    bf16x8 kfB = *(const bf16x8*)&Kt[(k0 + 16 + l16) * KP + quad * 8];
    PU pw[2];
    #pragma unroll
    for (int i = 0; i < 2; i++) {
      f32x4 sA = __builtin_amdgcn_mfma_f32_16x16x32_bf16(kfA, qf[i], (f32x4){0.f,0.f,0.f,0.f}, 0, 0, 0);
      f32x4 sB = __builtin_amdgcn_mfma_f32_16x16x32_bf16(kfB, qf[i], (f32x4){0.f,0.f,0.f,0.f}, 0, 0, 0);
      float p0 = fexp2(fminf(sA[0], 86.5f));
      float p1 = fexp2(fminf(sA[1], 86.5f));
      float p2 = fexp2(fminf(sA[2], 86.5f));
      float p3 = fexp2(fminf(sA[3], 86.5f));
      float p4 = fexp2(fminf(sB[0], 86.5f));
      float p5 = fexp2(fminf(sB[1], 86.5f));
      float p6 = fexp2(fminf(sB[2], 86.5f));
      float p7 = fexp2(fminf(sB[3], 86.5f));
      lsum[i] += ((p0 + p1) + (p2 + p3)) + ((p4 + p5) + (p6 + p7));
      pw[i].u[0] = cvtpk(p0, p1); pw[i].u[1] = cvtpk(p2, p3);
      pw[i].u[2] = cvtpk(p4, p5); pw[i].u[3] = cvtpk(p6, p7);
    }
    #pragma unroll
    for (int dt = 0; dt < 2; dt++) {
      int drow = (dt * 16 + l16) * VP;
      VU vu;
      vu.a[0] = *(const uint2*)&Vt[drow + k0 + quad * 4];
      vu.a[1] = *(const uint2*)&Vt[drow + k0 + 16 + quad * 4];
      #pragma unroll
      for (int i = 0; i < 2; i++)
        O[dt][i] = __builtin_amdgcn_mfma_f32_16x16x32_bf16(vu.v, pw[i].v, O[dt][i], 0, 0, 0);
    }
  }

  #pragma unroll
  for (int i = 0; i < 2; i++) {
    float l = lsum[i];
    l += __shfl_xor(l, 16);
    l += __shfl_xor(l, 32);
    lsum[i] = 1.f / l;
  }

  #pragma unroll
  for (int i = 0; i < 2; i++) {
    size_t node = (size_t)g * 512 + q0 + i * 16 + l16;
    #pragma unroll
    for (int dt = 0; dt < 2; dt++) {
      uint2 o;
      o.x = cvtpk(O[dt][i][0] * lsum[i], O[dt][i][1] * lsum[i]);
      o.y = cvtpk(O[dt][i][2] * lsum[i], O[dt][i][3] * lsum[i]);
      *(uint2*)(attn + node * 128 + hh * 32 + dt * 16 + quad * 4) = o;
    }
  }
}

// ---------------- workspace layout (bytes), total 103 MB ----------------
constexpr size_t KB = 1024;
constexpr size_t MB = 1048576;
constexpr size_t OFF_WT    = 0;                 // 576 KB
constexpr size_t OFF_CDT   = 576 * KB;          // 128 KB (cnt_dst totals)
constexpr size_t OFF_RP    = 704 * KB;          // 128 KB
constexpr size_t OFF_DIS   = 832 * KB;          // 128 KB
constexpr size_t OFF_MT    = 960 * KB;          // 32 KB
constexpr size_t OFF_STATS = 1024 * KB;         // 3 KB  [zeroed]
constexpr size_t OFF_CEI   = 6  * MB;           // 4 MB
constexpr size_t OFF_EP    = 10 * MB;           // 4 MB (packed int2 per slot)
constexpr size_t OFF_CANX  = 14 * MB;           // 8 MB; later comb
constexpr size_t OFF_CANU  = 22 * MB;           // 8 MB; later h1
constexpr size_t OFF_CANS  = 30 * MB;           // ~0.6 MB
constexpr size_t OFF_F1    = 31 * MB;           // fp32 16 MB
constexpr size_t OFF_HPROJ = 39 * MB;           // 8 MB
constexpr size_t OFF_TBIG  = 47 * MB;           // 40 MB; later qkv/mlph
constexpr size_t OFF_PARTH = OFF_TBIG;          // 8 MB hist partials (dead before Tbig)
constexpr size_t OFF_OFF2  = OFF_TBIG + 8 * MB; // 8 MB per-block slot bases
constexpr size_t OFF_PARTS = 87 * MB;           // 8 MB; attnb shares; end 103 MB

extern "C" void kernel_launch(void* const* d_in, const int* in_sizes, int n_in,
                              void* d_out, int out_size, void* d_ws, size_t ws_size,
                              hipStream_t stream) {
  (void)in_sizes; (void)n_in; (void)out_size; (void)ws_size;
  const uint* lmraw = (const uint*)d_in[3];
  const int*  ei    = (const int*)d_in[30];

  char* W = (char*)d_ws;
  ushort* wt    = (ushort*)(W + OFF_WT);
  int*    cdt   = (int*)(W + OFF_CDT);
  int*    rp    = (int*)(W + OFF_RP);
  float*  dis   = (float*)(W + OFF_DIS);
  ushort* MT    = (ushort*)(W + OFF_MT);
  float*  stats = (float*)(W + OFF_STATS);
  int*    cei   = (int*)(W + OFF_CEI);
  int2*   ep    = (int2*)(W + OFF_EP);
  ushort* part  = (ushort*)(W + OFF_PARTH);
  int*    off2  = (int*)(W + OFF_OFF2);
  ushort* canx  = (ushort*)(W + OFF_CANX);
  ushort* canu  = (ushort*)(W + OFF_CANU);
  ushort* cs    = (ushort*)(W + OFF_CANS);
  float*  F1    = (float*)(W + OFF_F1);
  ushort* hproj = (ushort*)(W + OFF_HPROJ);
  ushort* Tbig  = (ushort*)(W + OFF_TBIG);
  ushort* qkvb  = (ushort*)(W + OFF_TBIG);
  float*  parts = (float*)(W + OFF_PARTS);
  ushort* attnb = (ushort*)(W + OFF_PARTS);
  ushort* h1    = (ushort*)(W + OFF_CANU);
  ushort* comb  = (ushort*)(W + OFF_CANX);

  const ushort* cLambda = cs + COF[0];
  const ushort* cLmx    = cs + COF[1];
  const ushort* cBspa1  = cs + COF[3];
  const ushort* cBspa2  = cs + COF[5];
  const ushort* cBspe1  = cs + COF[7];
  const ushort* cBspe2  = cs + COF[9];
  const ushort* cChebB  = cs + COF[11];
  const ushort* cGam    = cs + COF[12];
  const ushort* cBqkv   = cs + COF[15];
  const ushort* cBout   = cs + COF[17];
  const ushort* cMb1    = cs + COF[19];
  const ushort* cMb2    = cs + COF[21];
  const ushort* cBn1w   = cs + COF[22];
  const ushort* cBn1b   = cs + COF[23];
  const ushort* cBn2w   = cs + COF[24];
  const ushort* cBn2b   = cs + COF[25];
  const ushort* cBn3w   = cs + COF[26];
  const ushort* cBn3b   = cs + COF[27];

  const ushort* NUL = nullptr;

  // only BN stats need zeroing (768 floats)
  zero_kernel<<<3, 256, 0, stream>>>((int*)(W + OFF_STATS), 768);

  // ---- canonicalize inputs ----
  CvtArgs ca;
  ca.src[0]  = d_in[2];  ca.src[1]  = d_in[3];  ca.src[2]  = d_in[4];
  ca.src[3]  = d_in[5];  ca.src[4]  = d_in[6];  ca.src[5]  = d_in[7];
  ca.src[6]  = d_in[8];  ca.src[7]  = d_in[9];  ca.src[8]  = d_in[10];
  ca.src[9]  = d_in[11]; ca.src[10] = d_in[12]; ca.src[11] = d_in[13];
  ca.src[12] = d_in[14]; ca.src[13] = d_in[15]; ca.src[14] = d_in[16];
  ca.src[15] = d_in[17]; ca.src[16] = d_in[18]; ca.src[17] = d_in[19];
  ca.src[18] = d_in[20]; ca.src[19] = d_in[21]; ca.src[20] = d_in[22];
  ca.src[21] = d_in[23]; ca.src[22] = d_in[24]; ca.src[23] = d_in[25];
  ca.src[24] = d_in[26]; ca.src[25] = d_in[27]; ca.src[26] = d_in[28];
  ca.src[27] = d_in[29];
  convert_small<<<(CAN_SMALL_TOTAL + 255) / 256, 256, 0, stream>>>(ca, cs, lmraw);
  convert_big<<<(2 * N * C / 4) / 256, 256, 0, stream>>>(d_in[0], d_in[1], canx, canu, lmraw);

  transpose_weights<<<1152, 256, 0, stream>>>(cs + COF[2], cs + COF[4], cs + COF[6],
      cs + COF[8], cs + COF[13], cs + COF[10], cs + COF[14], cs + COF[16],
      cs + COF[18], cs + COF[20], wt);

  // ---- edge prep (LDS-private histograms, no device-scope atomics) ----
  hist_lds<<<2 * HB, 1024, 0, stream>>>(ei, cei, part);
  reduce_cnt<<<N / 256, 256, 0, stream>>>(part, cdt, dis);
  scan_kernel<<<1, 1024, 0, stream>>>(cdt, rp);
  off_kernel<<<N / 256, 256, 0, stream>>>(rp, part, off2);
  edge_scatter<<<HB, 1024, 0, stream>>>(cei, off2, dis, ep);

  dim3 g1(512), g3(1536), bb(256);
  // ---- fused input MLP chains ----
  // spa: T0 = relu(x@spa1+b)@spa2+b  -> Tbig col-block 0 (stride 640)
  gemm_chain<false, 640><<<g1, bb, 0, stream>>>(canx, wt + WT_SPA1, cBspa1,
      wt + WT_SPA2, cBspa2, NUL, Tbig);
  // spe: hproj = (relu(x@spe1+b)@spe2+b)@proj  (stride 128)
  gemm_chain<true, 128><<<g1, bb, 0, stream>>>(canx, wt + WT_SPE1, cBspe1,
      wt + WT_SPE2, cBspe2, wt + WT_PROJ, hproj);

  // ---- spectral filter M^T ----
  ut_mfma<<<UT_BLOCKS, 256, 0, stream>>>(canu, hproj, parts);
  reduce_mt<<<64, 256, 0, stream>>>(parts, cLambda, cGam, MT);

  // ---- Chebyshev recurrence into Tbig, then one K=640 GEMM -> F1 ----
  spmm_cheb<<<N / 4, 256, 0, stream>>>(rp, ep, Tbig,       NUL,        Tbig + 128, cLmx, 1, 640);
  spmm_cheb<<<N / 4, 256, 0, stream>>>(rp, ep, Tbig + 128, Tbig,       Tbig + 256, cLmx, 0, 640);
  spmm_cheb<<<N / 4, 256, 0, stream>>>(rp, ep, Tbig + 256, Tbig + 128, Tbig + 384, cLmx, 0, 640);
  spmm_cheb<<<N / 4, 256, 0, stream>>>(rp, ep, Tbig + 384, Tbig + 256, Tbig + 512, cLmx, 0, 640);
  gemm_lds<640,128,false,1,true ,false,640,128,false><<<g1, bb, 0, stream>>>(Tbig, wt + WT_CHEB, cChebB, NUL, F1);

  // ---- out_spectral + x residual; BN1 -> h1 ----
  gemm_lds<128,128,false,2,false,true ,128,128,false><<<g1, bb, 0, stream>>>(canu, MT, NUL, canx, F1);
  bn_stats<<<256, 256, 0, stream>>>(F1, stats);
  bn_apply<<<(N * C) / 1024, 256, 0, stream>>>(F1, stats, cBn1w, cBn1b, NUL, h1, lmraw, 0);

  // ---- attention branch (Q pre-scaled in QKV epilogue) ----
  gemm_lds<128,384,false,0,true ,false,128,384,true ><<<g3, bb, 0, stream>>>(canx, wt + WT_QKV, cBqkv, NUL, qkvb);
  attn_mfma<<<512, 512, 0, stream>>>(qkvb, attnb);
  gemm_lds<128,128,false,1,true ,true ,128,128,false><<<g1, bb, 0, stream>>>(attnb, wt + WT_WOUT, cBout, canx, F1);
  bn_stats<<<256, 256, 0, stream>>>(F1, stats + 256);
  bn_apply<<<(N * C) / 1024, 256, 0, stream>>>(F1, stats + 256, cBn2w, cBn2b, h1, comb, lmraw, 0);

  // ---- fused MLP + final BN ----
  gemm_mlp<<<g1, bb, 0, stream>>>(comb, wt + WT_MLP1, cMb1, wt + WT_MLP2, cMb2, comb, F1);
  bn_stats<<<256, 256, 0, stream>>>(F1, stats + 512);
  bn_apply<<<(N * C) / 1024, 256, 0, stream>>>(F1, stats + 512, cBn3w, cBn3b, NUL, d_out, lmraw, 1);
}